// Round 14
// baseline (388.864 us; speedup 1.0000x reference)
//
#include <hip/hip_runtime.h>
#include <math.h>

#define BB 8
#define NN 1024
#define KK 16
#define NKP (NN*KK)
#define BN_INV 0.99999500003749981f

typedef unsigned short u16;
typedef __attribute__((ext_vector_type(8))) short short8;
typedef __attribute__((ext_vector_type(4))) float f32x4;

#define MFMA16(a,b,c) __builtin_amdgcn_mfma_f32_16x16x32_bf16(a,b,c,0,0,0)

__device__ __forceinline__ float lrelu(float v) { return v >= 0.f ? v : 0.2f * v; }

__device__ __forceinline__ u16 f2bf(float f) {
  union { float f; unsigned u; } v; v.f = f;
  unsigned r = v.u + 0x7fff + ((v.u >> 16) & 1);
  return (u16)(r >> 16);
}
__device__ __forceinline__ float bf2f(u16 s) {
  union { unsigned u; float f; } v; v.u = ((unsigned)s) << 16;
  return v.f;
}

// ---------------- workspace byte offsets ----------------
constexpr size_t OFF_IDX   = 0;          // int[8*1024*16]
constexpr size_t OFF_X1P   = 524288;     // bf16 [8][1024][64]
constexpr size_t OFF_X2P   = 1572864;
constexpr size_t OFF_X3P   = 2621440;    // bf16 [8][1024][128]  (aliased as MUV during mak)
constexpr size_t OFF_MUV   = 2621440;    // bf16 [8][1024][128] u|v
constexpr size_t OFF_X4P   = 4718592;    // bf16 [8][1024][256]
constexpr size_t OFF_PMAX  = 8912896;    // f32 [8][16][1024]
constexpr size_t OFF_PSUM  = 9437184;
constexpr size_t OFF_XP    = 9961472;    // f32 [8][2048]
constexpr size_t OFF_XF1   = 10027008;   // f32 [8][512]
constexpr size_t OFF_XF2   = 10043392;   // f32 [8][256]
constexpr size_t OFF_M1WM  = 10055680;   // bf16 [2][64][32]
constexpr size_t OFF_M1W1S = 10063872;   // bf16 [13][64][32]
constexpr size_t OFF_M2W0S = 10117120;   // bf16 [2][128][32] stacked [Wd;Wc-Wd]
constexpr size_t OFF_M2WM  = 10133504;   // bf16 [2][64][32]
constexpr size_t OFF_M2W1S = 10141696;   // bf16 [13][64][32]
constexpr size_t OFF_W3S   = 10194944;   // bf16 [2][256][32] stacked
constexpr size_t OFF_W4S   = 10227712;   // bf16 [4][512][32] stacked
constexpr size_t OFF_W5    = 10358784;   // bf16 [16][1024][32]
constexpr size_t OFF_WL1T  = 11407360;   // f32 [2048][512]
constexpr size_t OFF_WL2T  = 15601664;   // f32 [512][256]
constexpr size_t OFF_WL3T  = 16125952;   // f32 [256][49]
constexpr size_t OFF_UV3   = 16177152;   // bf16 [8][1024][256] conv3 u|v
constexpr size_t OFF_UV4   = 20371456;   // bf16 [8][1024][512] conv4 u|v

// ---------------- weight prep ----------------
struct SSeg { const float* w; const float* g; u16* dst; int O; int C; int cpl2; int ch; int stk; int start; };
struct SArgs { SSeg seg[6]; int total; };

__global__ __launch_bounds__(256) void prep_scale_bf16(SArgs a) {
  const int tid = blockIdx.x * 256 + threadIdx.x;
  if (tid >= a.total) return;
  int s = 0;
  #pragma unroll
  for (int i = 1; i < 6; ++i) if (tid >= a.seg[i].start) s = i;
  const SSeg sg = a.seg[s];
  const int e = tid - sg.start;
  const int o2 = e >> sg.cpl2;
  const int c = e & ((1 << sg.cpl2) - 1);
  float v = 0.f;
  if (sg.stk) {
    const int half = sg.O >> 1;
    const int o = o2 & (half - 1);
    const int CIN = 2 * sg.C;
    const float wd = sg.w[o * CIN + c];
    v = (o2 < half) ? wd : (sg.w[o * CIN + sg.C + c] - wd);
    v *= sg.g[o] * BN_INV;
  } else if (c < sg.C) {
    v = sg.w[o2 * sg.C + c];
    if (sg.ch && c >= sg.ch) v -= sg.w[o2 * sg.C + c - sg.ch];
    v *= sg.g[o2] * BN_INV;
  }
  sg.dst[(size_t)(c >> 5) * (sg.O * 32) + o2 * 32 + (c & 31)] = f2bf(v);
}

// w1s virtual-channel weights, chunk-major [13][64][32]
__global__ __launch_bounds__(256) void prep_w1s_bf16(
    const float* __restrict__ w1a, const float* __restrict__ wsa,
    const float* __restrict__ goa, const float* __restrict__ gsa,
    const float* __restrict__ w1b, const float* __restrict__ wsb,
    const float* __restrict__ gob, const float* __restrict__ gsb,
    u16* __restrict__ dsta, u16* __restrict__ dstb) {
  const int tid = blockIdx.x * 256 + threadIdx.x;
  if (tid >= 64 * 416) return;
  const float* w1 = blockIdx.y ? w1b : w1a;
  const float* wsm = blockIdx.y ? wsb : wsa;
  const float* go = blockIdx.y ? gob : goa;
  const float* gs = blockIdx.y ? gsb : gsa;
  u16* dst = blockIdx.y ? dstb : dsta;
  const int o = tid / 416, ci = tid - o * 416;
  float v = 0.f;
  if (ci < 384) {
    const int ii = ci >> 6, ch = ci & 63;
    const int base = (o * 24 + ii * 4) * 64 + ch;
    v = go[o] * BN_INV * (w1[base] + w1[base + 64] + w1[base + 128] + w1[base + 192]);
  } else if (ci < 390) {
    v = gs[o] * BN_INV * wsm[o * 6 + (ci - 384)];
  }
  dst[(size_t)(ci >> 5) * 2048 + o * 32 + (ci & 31)] = f2bf(v);
}

struct TSeg { const float* w; const float* g; float* dst; int O; int C; int start; };
struct TArgs3 { TSeg seg[3]; int total; };

__global__ __launch_bounds__(256) void prep_transpose_f32(TArgs3 a) {
  const int tid = blockIdx.x * 256 + threadIdx.x;
  if (tid >= a.total) return;
  int s = 0;
  #pragma unroll
  for (int i = 1; i < 3; ++i) if (tid >= a.seg[i].start) s = i;
  const TSeg sg = a.seg[s];
  const int e = tid - sg.start;
  const int c = e / sg.O;
  const int o = e - c * sg.O;
  float v = sg.w[o * sg.C + c];
  if (sg.g) v *= sg.g[o] * BN_INV;
  sg.dst[e] = v;
}

// ---------------- KNN (exact fp32) ----------------
__global__ __launch_bounds__(256) void knn_kernel(const float* __restrict__ x, int* __restrict__ idxout) {
  const int wid  = (blockIdx.x * blockDim.x + threadIdx.x) >> 6;
  const int lane = threadIdx.x & 63;
  const int b = wid >> 10;
  const int n = wid & (NN - 1);
  const float* xb = x + b * 3 * NN;
  const float x0n = xb[n], x1n = xb[NN + n], x2n = xb[2 * NN + n];
  const float xxn = x0n * x0n + x1n * x1n + x2n * x2n;
  float pd[16];
  #pragma unroll
  for (int j = 0; j < 16; ++j) {
    const int m = j * 64 + lane;
    const float x0 = xb[m], x1 = xb[NN + m], x2 = xb[2 * NN + m];
    const float dot = x0n * x0 + x1n * x1 + x2n * x2;
    const float xxm = x0 * x0 + x1 * x1 + x2 * x2;
    pd[j] = 2.f * dot - xxn - xxm;
  }
  for (int r = 0; r < 16; ++r) {
    float bv = pd[0]; int bj = 0;
    #pragma unroll
    for (int j = 1; j < 16; ++j) if (pd[j] > bv) { bv = pd[j]; bj = j; }
    int bm = bj * 64 + lane;
    #pragma unroll
    for (int off = 32; off > 0; off >>= 1) {
      const float ov = __shfl_down(bv, off);
      const int   om = __shfl_down(bm, off);
      if (ov > bv || (ov == bv && om < bm)) { bv = ov; bm = om; }
    }
    bm = __shfl(bm, 0);
    if (lane == 0) idxout[wid * KK + r] = bm;
    const int  cj   = bm >> 6;
    const bool mine = (bm & 63) == lane;
    #pragma unroll
    for (int j = 0; j < 16; ++j) if (mine && j == cj) pd[j] = -INFINITY;
  }
}

// ---------------- helpers ----------------
__device__ __forceinline__ short8 bfrag64(const u16* T, int pl, int quad, int c0) {
  const int pos = ((c0 >> 3) + quad) ^ (pl & 7);
  return *(const short8*)(T + pl * 64 + pos * 8);
}
__device__ __forceinline__ void writeD64(u16* T, int pl, int quad, const f32x4 a,
                                         const float* __restrict__ bias, int obase) {
  union { ushort4 v; u16 s[4]; } pk;
  #pragma unroll
  for (int r = 0; r < 4; ++r) pk.s[r] = f2bf(lrelu(a[r] + bias[obase + quad * 4 + r]));
  const int g = (obase + quad * 4) >> 3;
  const int pos = g ^ (pl & 7);
  *(ushort4*)(T + pl * 64 + pos * 8 + (quad & 1) * 4) = pk.v;
}

// ---------------- mak1 UV ----------------
__global__ __launch_bounds__(256) void mak1_uv(
    const float* __restrict__ x, const float* __restrict__ w0,
    const float* __restrict__ g0, const float* __restrict__ b0,
    u16* __restrict__ MUV) {
  const int tid = blockIdx.x * 256 + threadIdx.x;
  if (tid >= BB * NN * 64) return;
  const int o = tid & 63;
  const int p = tid >> 6;
  const int b = p >> 10, n = p & (NN - 1);
  const float* xb = x + b * 3 * NN;
  const float gg = g0[o] * BN_INV;
  float u = 0.f, v = 0.f;
  #pragma unroll
  for (int i = 0; i < 3; ++i) {
    const float wd = w0[o * 6 + i];
    const float wc = w0[o * 6 + 3 + i];
    const float c = xb[i * NN + n];
    u += wd * c;
    v += (wc - wd) * c;
  }
  MUV[(size_t)p * 128 + o]      = f2bf(gg * u);
  MUV[(size_t)p * 128 + 64 + o] = f2bf(gg * v + b0[o]);
}

// ---------------- mak23 fused: 2 points/wave (low reg pressure, 2x grid) ----------------
// one-shot u/v gather -> y0 in regs -> GEMM2 -> GEMM3; no barriers (wave-private LDS)
__global__ __launch_bounds__(256) void mak23_mfma(
    const float* __restrict__ x, const int* __restrict__ idxb, const u16* __restrict__ MUV,
    const u16* __restrict__ wmb, const float* __restrict__ bmv,
    const u16* __restrict__ w1s, const float* __restrict__ bov, const float* __restrict__ bsv,
    u16* __restrict__ Xoutp) {
  __shared__ __align__(16) u16 YMs[4][32 * 64];   // 16 KB: 2 16-row tiles per wave

  const int t = threadIdx.x;
  const int b = blockIdx.z;
  const int w = t >> 6, l = t & 63;
  const int quad = l >> 4, l15 = l & 15;
  const int cq8 = quad * 8;
  const int p0 = blockIdx.x * 8 + w * 2;   // 2 points for this wave
  u16* myYM = YMs[w];
  const float* xb = x + b * 3 * NN;

  // one-shot: idx, geo, u/v rows for the wave's 2 edges (lane l15 = k)
  int nbr[2];
  #pragma unroll
  for (int pg = 0; pg < 2; ++pg)
    nbr[pg] = idxb[(size_t)(b * NN + p0 + pg) * 16 + l15] & (NN - 1);

  float ge[2][6];
  short8 bgv[2];
  #pragma unroll
  for (int pg = 0; pg < 2; ++pg) {
    const int ctr = p0 + pg;
    union { short8 v; u16 s[8]; } gq;
    gq.v = (short8)(short)0;
    #pragma unroll
    for (int i = 0; i < 3; ++i) {
      const float fc = xb[i * NN + ctr];
      ge[pg][i]     = xb[i * NN + nbr[pg]] - fc;
      ge[pg][3 + i] = fc;
      gq.s[i]     = f2bf(ge[pg][i]);
      gq.s[3 + i] = f2bf(ge[pg][3 + i]);
    }
    bgv[pg] = (quad == 0) ? gq.v : (short8)(short)0;
  }

  // y0 B-frags: lrelu(u[nbr] + v[ctr])
  short8 bf[2][2];
  #pragma unroll
  for (int pg = 0; pg < 2; ++pg) {
    const u16* urow = MUV + (size_t)(b * NN + nbr[pg]) * 128;
    const u16* vrow = MUV + (size_t)(b * NN + p0 + pg) * 128 + 64;
    #pragma unroll
    for (int kc = 0; kc < 2; ++kc) {
      union { short8 v; u16 s[8]; } uu, vv, rr;
      uu.v = *(const short8*)(urow + kc * 32 + cq8);
      vv.v = *(const short8*)(vrow + kc * 32 + cq8);
      #pragma unroll
      for (int j = 0; j < 8; ++j) rr.s[j] = f2bf(lrelu(bf2f(uu.s[j]) + bf2f(vv.s[j])));
      bf[pg][kc] = rr.v;
    }
  }

  // ---- GEMM2: A-loads shared across pg ----
  #pragma unroll
  for (int at = 0; at < 4; ++at) {
    f32x4 a2[2];
    #pragma unroll
    for (int pg = 0; pg < 2; ++pg) a2[pg] = (f32x4)0.f;
    #pragma unroll
    for (int kc = 0; kc < 2; ++kc) {
      const short8 af = *(const short8*)(wmb + (size_t)(kc * 64 + at * 16 + l15) * 32 + cq8);
      #pragma unroll
      for (int pg = 0; pg < 2; ++pg) a2[pg] = MFMA16(af, bf[pg][kc], a2[pg]);
    }
    #pragma unroll
    for (int pg = 0; pg < 2; ++pg) writeD64(myYM, pg * 16 + l15, quad, a2[pg], bmv, at * 16);
  }
  // wave-private LDS rows -> no barrier (lgkmcnt orders write->read)

  // ---- GEMM3: B-frags in regs; each af load feeds 2 MFMAs ----
  short8 bf3[2][2];
  #pragma unroll
  for (int pg = 0; pg < 2; ++pg)
    #pragma unroll
    for (int kc = 0; kc < 2; ++kc)
      bf3[pg][kc] = bfrag64(myYM, pg * 16 + l15, quad, kc * 32);

  f32x4 acc[2][4];
  #pragma unroll
  for (int pg = 0; pg < 2; ++pg)
    #pragma unroll
    for (int at = 0; at < 4; ++at) acc[pg][at] = (f32x4)0.f;

  #pragma unroll
  for (int ii = 0; ii < 6; ++ii) {
    f32x4 tac[2][4];
    #pragma unroll
    for (int pg = 0; pg < 2; ++pg)
      #pragma unroll
      for (int at = 0; at < 4; ++at) tac[pg][at] = (f32x4)0.f;
    #pragma unroll
    for (int kc = 0; kc < 2; ++kc) {
      #pragma unroll
      for (int at = 0; at < 4; ++at) {
        const short8 af = *(const short8*)(w1s + (size_t)((ii * 2 + kc) * 64 + at * 16 + l15) * 32 + cq8);
        #pragma unroll
        for (int pg = 0; pg < 2; ++pg) tac[pg][at] = MFMA16(af, bf3[pg][kc], tac[pg][at]);
      }
    }
    #pragma unroll
    for (int pg = 0; pg < 2; ++pg) {
      const float g = ge[pg][ii];
      #pragma unroll
      for (int at = 0; at < 4; ++at) acc[pg][at] += g * tac[pg][at];
    }
  }
  #pragma unroll
  for (int at = 0; at < 4; ++at) {
    const short8 af = *(const short8*)(w1s + (size_t)(12 * 64 + at * 16 + l15) * 32 + cq8);
    #pragma unroll
    for (int pg = 0; pg < 2; ++pg) acc[pg][at] = MFMA16(af, bgv[pg], acc[pg][at]);
  }

  // ---- epilogue: bias + lrelu, max over k=l15, per pg ----
  #pragma unroll
  for (int pg = 0; pg < 2; ++pg) {
    u16* orow = Xoutp + (size_t)(b * NN + p0 + pg) * 64;
    #pragma unroll
    for (int at = 0; at < 4; ++at) {
      union { ushort4 v; u16 s[4]; } pk;
      #pragma unroll
      for (int r = 0; r < 4; ++r) {
        const int o = at * 16 + quad * 4 + r;
        float v = lrelu(acc[pg][at][r] + bov[o] + bsv[o]);
        v = fmaxf(v, __shfl_xor(v, 1));
        v = fmaxf(v, __shfl_xor(v, 2));
        v = fmaxf(v, __shfl_xor(v, 4));
        v = fmaxf(v, __shfl_xor(v, 8));
        pk.s[r] = f2bf(v);
      }
      if (l15 == 0) *(ushort4*)(orow + at * 16 + quad * 4) = pk.v;
    }
  }
}

// ---------------- dense UV GEMM ----------------
template<int CH, int COUT2>
__global__ __launch_bounds__(256) void dense_uv(
    const u16* __restrict__ srcp, const u16* __restrict__ w2,
    const float* __restrict__ bias, u16* __restrict__ UV) {
  constexpr int COUT = COUT2 / 2;
  constexpr int NCH = CH / 32;
  const int t = threadIdx.x;
  const int b = blockIdx.z;
  const int w = t >> 6, l = t & 63;
  const int quad = l >> 4, l15 = l & 15;
  const int cq8 = quad * 8;
  int n0, ow0;
  if constexpr (COUT2 >= 256) { n0 = blockIdx.x * 64; ow0 = blockIdx.y * 256 + w * 64; }
  else { n0 = blockIdx.x * 128 + (w >> 1) * 64; ow0 = (w & 1) * 64; }

  f32x4 acc[4][4];
  #pragma unroll
  for (int i = 0; i < 4; ++i)
    #pragma unroll
    for (int j = 0; j < 4; ++j) acc[i][j] = (f32x4)0.f;

  #pragma unroll
  for (int k = 0; k < NCH; ++k) {
    short8 bfr[4];
    #pragma unroll
    for (int pg = 0; pg < 4; ++pg) {
      const int n = n0 + pg * 16 + l15;
      bfr[pg] = *(const short8*)(srcp + (size_t)(b * NN + n) * CH + k * 32 + cq8);
    }
    #pragma unroll
    for (int at = 0; at < 4; ++at) {
      const short8 af = *(const short8*)(w2 + ((size_t)(k * COUT2 + ow0 + at * 16 + l15)) * 32 + cq8);
      #pragma unroll
      for (int pg = 0; pg < 4; ++pg) acc[at][pg] = MFMA16(af, bfr[pg], acc[at][pg]);
    }
  }

  #pragma unroll
  for (int at = 0; at < 4; ++at) {
    const int o0 = ow0 + at * 16 + quad * 4;
    const bool isv = (o0 >= COUT);
    float bb[4];
    #pragma unroll
    for (int r = 0; r < 4; ++r) bb[r] = isv ? bias[o0 + r - COUT] : 0.f;
    #pragma unroll
    for (int pg = 0; pg < 4; ++pg) {
      const int n = n0 + pg * 16 + l15;
      union { ushort4 v; u16 s[4]; } pk;
      #pragma unroll
      for (int r = 0; r < 4; ++r) pk.s[r] = f2bf(acc[at][pg][r] + bb[r]);
      *(ushort4*)(UV + (size_t)(b * NN + n) * COUT2 + o0) = pk.v;
    }
  }
}

// ---------------- gather-max ----------------
__device__ __forceinline__ float4 ubf4(ushort4 q) {
  float4 f;
  f.x = bf2f(q.x); f.y = bf2f(q.y); f.z = bf2f(q.z); f.w = bf2f(q.w);
  return f;
}

template<int COUT>
__global__ __launch_bounds__(256) void gather_max(
    const u16* __restrict__ UV, const int* __restrict__ idxb,
    u16* __restrict__ Xoutp) {
  constexpr int CG = COUT / 4;
  const int tid = blockIdx.x * 256 + threadIdx.x;
  const int cg = tid & (CG - 1);
  const int P = tid / CG;
  const int b = P >> 10;
  const int n = P & (NN - 1);

  const float4 vv = ubf4(*(const ushort4*)(UV + (size_t)P * (2 * COUT) + COUT + 4 * cg));
  const int4* ip = (const int4*)(idxb + (size_t)b * NKP + n * 16);
  float4 m = {-INFINITY, -INFINITY, -INFINITY, -INFINITY};
  #pragma unroll
  for (int kq = 0; kq < 4; ++kq) {
    const int4 iv = ip[kq];
    const int mr[4] = { iv.x & (NN - 1), iv.y & (NN - 1), iv.z & (NN - 1), iv.w & (NN - 1) };
    ushort4 uq[4];
    #pragma unroll
    for (int j = 0; j < 4; ++j)
      uq[j] = *(const ushort4*)(UV + (size_t)(b * NN + mr[j]) * (2 * COUT) + 4 * cg);
    #pragma unroll
    for (int j = 0; j < 4; ++j) {
      const float4 uu = ubf4(uq[j]);
      float4 s;
      s.x = uu.x + vv.x; s.y = uu.y + vv.y; s.z = uu.z + vv.z; s.w = uu.w + vv.w;
      m.x = fmaxf(m.x, fmaxf(s.x, 0.2f * s.x));
      m.y = fmaxf(m.y, fmaxf(s.y, 0.2f * s.y));
      m.z = fmaxf(m.z, fmaxf(s.z, 0.2f * s.z));
      m.w = fmaxf(m.w, fmaxf(s.w, 0.2f * s.w));
    }
  }
  union { ushort4 v; u16 s[4]; } pk;
  pk.s[0] = f2bf(m.x); pk.s[1] = f2bf(m.y); pk.s[2] = f2bf(m.z); pk.s[3] = f2bf(m.w);
  *(ushort4*)(Xoutp + (size_t)P * COUT + 4 * cg) = pk.v;
}

// ---------------- conv5 ----------------
__global__ __launch_bounds__(256) void conv5_mfma(
    const u16* __restrict__ X1P, const u16* __restrict__ X2P,
    const u16* __restrict__ X3P, const u16* __restrict__ X4P,
    const u16* __restrict__ w5b, const float* __restrict__ b5,
    float* __restrict__ PMAX, float* __restrict__ PSUM) {
  const int t = threadIdx.x;
  const int b = blockIdx.z;
  const int n0 = blockIdx.x * 64;
  const int w = t >> 6, l = t & 63;
  const int quad = l >> 4, l15 = l & 15;
  const int cq8 = quad * 8;
  const int ow0 = blockIdx.y * 256 + w * 64;

  f32x4 acc[4][4];
  #pragma unroll
  for (int i = 0; i < 4; ++i)
    #pragma unroll
    for (int j = 0; j < 4; ++j) acc[i][j] = (f32x4)0.f;

  #pragma unroll 4
  for (int k = 0; k < 16; ++k) {
    const int c = k * 32 + cq8;
    short8 bfr[4];
    #pragma unroll
    for (int pg = 0; pg < 4; ++pg) {
      const int n = n0 + pg * 16 + l15;
      const u16* src; int cc;
      if (c < 64)       { src = X1P + (size_t)(b * NN + n) * 64;  cc = c; }
      else if (c < 128) { src = X2P + (size_t)(b * NN + n) * 64;  cc = c - 64; }
      else if (c < 256) { src = X3P + (size_t)(b * NN + n) * 128; cc = c - 128; }
      else              { src = X4P + (size_t)(b * NN + n) * 256; cc = c - 256; }
      bfr[pg] = *(const short8*)(src + cc);
    }
    #pragma unroll
    for (int at = 0; at < 4; ++at) {
      const short8 af = *(const short8*)(w5b + ((size_t)(k * 1024 + ow0 + at * 16 + l15)) * 32 + cq8);
      #pragma unroll
      for (int pg = 0; pg < 4; ++pg) acc[at][pg] = MFMA16(af, bfr[pg], acc[at][pg]);
    }
  }

  #pragma unroll
  for (int at = 0; at < 4; ++at) {
    f32x4 pmx, psm;
    #pragma unroll
    for (int r = 0; r < 4; ++r) {
      const float bb = b5[ow0 + at * 16 + quad * 4 + r];
      float m = -INFINITY, s = 0.f;
      #pragma unroll
      for (int pg = 0; pg < 4; ++pg) {
        const float v = lrelu(acc[at][pg][r] + bb);
        m = fmaxf(m, v); s += v;
      }
      #pragma unroll
      for (int msk = 1; msk < 16; msk <<= 1) {
        m = fmaxf(m, __shfl_xor(m, msk));
        s += __shfl_xor(s, msk);
      }
      pmx[r] = m; psm[r] = s;
    }
    if (l15 == 0) {
      float* dm = PMAX + (size_t)(b * 16 + blockIdx.x) * 1024 + ow0 + at * 16 + quad * 4;
      float* ds = PSUM + (size_t)(b * 16 + blockIdx.x) * 1024 + ow0 + at * 16 + quad * 4;
      *(f32x4*)dm = pmx;
      *(f32x4*)ds = psm;
    }
  }
}

__global__ __launch_bounds__(256) void reduce5(const float* __restrict__ PMAX, const float* __restrict__ PSUM,
                                               float* __restrict__ XPg) {
  const int tid = blockIdx.x * 256 + threadIdx.x;
  const int b = tid >> 10, o = tid & 1023;
  float m = -INFINITY, s = 0.f;
  for (int pt = 0; pt < 16; ++pt) {
    m = fmaxf(m, PMAX[(size_t)(b * 16 + pt) * 1024 + o]);
    s += PSUM[(size_t)(b * 16 + pt) * 1024 + o];
  }
  XPg[b * 2048 + o] = m;
  XPg[b * 2048 + 1024 + o] = s * (1.f / 1024.f);
}

// ---------------- FC head ----------------
__global__ __launch_bounds__(256) void fc1_kernel(const float* __restrict__ XPg, const float* __restrict__ wl1t,
                                                  const float* __restrict__ bn4_b, float* __restrict__ XF1) {
  __shared__ float red[64 * 5];
  const int t = threadIdx.x;
  const int b = blockIdx.y;
  const int o = blockIdx.x * 64 + (t & 63);
  const int cq = t >> 6;
  const float* xp = XPg + b * 2048;
  float acc = 0.f;
  for (int c = cq * 512; c < cq * 512 + 512; ++c) acc = fmaf(wl1t[c * 512 + o], xp[c], acc);
  red[(t & 63) * 5 + cq] = acc;
  __syncthreads();
  if (t < 64) {
    const int oo = blockIdx.x * 64 + t;
    const float v = red[t * 5] + red[t * 5 + 1] + red[t * 5 + 2] + red[t * 5 + 3] + bn4_b[oo];
    XF1[b * 512 + oo] = lrelu(v);
  }
}

__global__ __launch_bounds__(256) void fc2_kernel(const float* __restrict__ XF1, const float* __restrict__ wl2t,
                                                  const float* __restrict__ bl2, const float* __restrict__ bn5_g,
                                                  const float* __restrict__ bn5_b, float* __restrict__ XF2) {
  __shared__ float red[64 * 5];
  const int t = threadIdx.x;
  const int b = blockIdx.y;
  const int o = blockIdx.x * 64 + (t & 63);
  const int cq = t >> 6;
  const float* xf = XF1 + b * 512;
  float acc = 0.f;
  for (int c = cq * 128; c < cq * 128 + 128; ++c) acc = fmaf(wl2t[c * 256 + o], xf[c], acc);
  red[(t & 63) * 5 + cq] = acc;
  __syncthreads();
  if (t < 64) {
    const int oo = blockIdx.x * 64 + t;
    const float bias = bl2[oo] * (bn5_g[oo] * BN_INV) + bn5_b[oo];
    const float v = red[t * 5] + red[t * 5 + 1] + red[t * 5 + 2] + red[t * 5 + 3] + bias;
    XF2[b * 256 + oo] = lrelu(v);
  }
}

__global__ __launch_bounds__(256) void fc3_kernel(const float* __restrict__ XF2, const float* __restrict__ wl3t,
                                                  const float* __restrict__ bl3, float* __restrict__ out) {
  __shared__ float red[64 * 5];
  const int t = threadIdx.x;
  const int b = blockIdx.y;
  const int ol = t & 63;
  const int cq = t >> 6;
  const float* xf = XF2 + b * 256;
  float acc = 0.f;
  if (ol < 49) for (int c = cq * 64; c < cq * 64 + 64; ++c) acc = fmaf(wl3t[c * 49 + ol], xf[c], acc);
  red[ol * 5 + cq] = acc;
  __syncthreads();
  if (t < 49) out[b * 49 + t] = red[t * 5] + red[t * 5 + 1] + red[t * 5 + 2] + red[t * 5 + 3] + bl3[t];
}

// ---------------- host ----------------
extern "C" void kernel_launch(void* const* d_in, const int* in_sizes, int n_in,
                              void* d_out, int out_size, void* d_ws, size_t ws_size,
                              hipStream_t stream) {
  (void)in_sizes; (void)n_in; (void)out_size; (void)ws_size;
  const float* x     = (const float*)d_in[0];
  const float* m1_w0 = (const float*)d_in[1];
  const float* m1_g0 = (const float*)d_in[2];
  const float* m1_b0 = (const float*)d_in[3];
  const float* m1_wm = (const float*)d_in[4];
  const float* m1_gm = (const float*)d_in[5];
  const float* m1_bm = (const float*)d_in[6];
  const float* m1_w1 = (const float*)d_in[7];
  const float* m1_go = (const float*)d_in[8];
  const float* m1_bo = (const float*)d_in[9];
  const float* m1_ws = (const float*)d_in[10];
  const float* m1_gs = (const float*)d_in[11];
  const float* m1_bs = (const float*)d_in[12];
  const float* m2_w0 = (const float*)d_in[13];
  const float* m2_g0 = (const float*)d_in[14];
  const float* m2_b0 = (const float*)d_in[15];
  const float* m2_wm = (const float*)d_in[16];
  const float* m2_gm = (const float*)d_in[17];
  const float* m2_bm = (const float*)d_in[18];
  const float* m2_w1 = (const float*)d_in[19];
  const float* m2_go = (const float*)d_in[20];
  const float* m2_bo = (const float*)d_in[21];
  const float* m2_ws = (const float*)d_in[22];
  const float* m2_gs = (const float*)d_in[23];
  const float* m2_bs = (const float*)d_in[24];
  const float* w3    = (const float*)d_in[25];
  const float* g3    = (const float*)d_in[26];
  const float* b3    = (const float*)d_in[27];
  const float* w4    = (const float*)d_in[28];
  const float* g4    = (const float*)d_in[29];
  const float* b4    = (const float*)d_in[30];
  const float* w5    = (const float*)d_in[31];
  const float* g5    = (const float*)d_in[32];
  const float* b5    = (const float*)d_in[33];
  const float* wl1   = (const float*)d_in[34];
  const float* bn4_g = (const float*)d_in[35];
  const float* bn4_b = (const float*)d_in[36];
  const float* wl2   = (const float*)d_in[37];
  const float* bl2   = (const float*)d_in[38];
  const float* bn5_g = (const float*)d_in[39];
  const float* bn5_b = (const float*)d_in[40];
  const float* wl3   = (const float*)d_in[41];
  const float* bl3   = (const float*)d_in[42];

  char* wsb = (char*)d_ws;
  int*  IDX  = (int*)(wsb + OFF_IDX);
  u16*  X1P  = (u16*)(wsb + OFF_X1P);
  u16*  X2P  = (u16*)(wsb + OFF_X2P);
  u16*  X3P  = (u16*)(wsb + OFF_X3P);
  u16*  X4P  = (u16*)(wsb + OFF_X4P);
  u16*  MUV  = (u16*)(wsb + OFF_MUV);
  float* PMAX = (float*)(wsb + OFF_PMAX);
  float* PSUM = (float*)(wsb + OFF_PSUM);
  float* XPg  = (float*)(wsb + OFF_XP);
  float* XF1  = (float*)(wsb + OFF_XF1);
  float* XF2  = (float*)(wsb + OFF_XF2);
  u16*  M1WM = (u16*)(wsb + OFF_M1WM);
  u16*  M1W1S = (u16*)(wsb + OFF_M1W1S);
  u16*  M2W0S = (u16*)(wsb + OFF_M2W0S);
  u16*  M2WM = (u16*)(wsb + OFF_M2WM);
  u16*  M2W1S = (u16*)(wsb + OFF_M2W1S);
  u16*  W3S  = (u16*)(wsb + OFF_W3S);
  u16*  W4S  = (u16*)(wsb + OFF_W4S);
  u16*  W5B  = (u16*)(wsb + OFF_W5);
  float* WL1T = (float*)(wsb + OFF_WL1T);
  float* WL2T = (float*)(wsb + OFF_WL2T);
  float* WL3T = (float*)(wsb + OFF_WL3T);
  u16*  UV3  = (u16*)(wsb + OFF_UV3);
  u16*  UV4  = (u16*)(wsb + OFF_UV4);

  SArgs sa; int st = 0;
  auto sset = [&](int i, const float* w, const float* g, u16* dst, int O, int C, int cpl2, int ch, int stk) {
    sa.seg[i].w = w; sa.seg[i].g = g; sa.seg[i].dst = dst; sa.seg[i].O = O; sa.seg[i].C = C;
    sa.seg[i].cpl2 = cpl2; sa.seg[i].ch = ch; sa.seg[i].stk = stk; sa.seg[i].start = st;
    st += O << cpl2;
  };
  sset(0, m1_wm, m1_gm, M1WM, 64, 64, 6, 0, 0);
  sset(1, m2_w0, m2_g0, M2W0S, 128, 64, 6, 0, 1);
  sset(2, m2_wm, m2_gm, M2WM, 64, 64, 6, 0, 0);
  sset(3, w3, g3, W3S, 256, 64, 6, 0, 1);
  sset(4, w4, g4, W4S, 512, 128, 7, 0, 1);
  sset(5, w5, g5, W5B, 1024, 512, 9, 0, 0);
  sa.total = st;

  TArgs3 ta; int tt = 0;
  auto tset = [&](int i, const float* w, const float* g, float* dst, int O, int C) {
    ta.seg[i].w = w; ta.seg[i].g = g; ta.seg[i].dst = dst; ta.seg[i].O = O; ta.seg[i].C = C;
    ta.seg[i].start = tt; tt += O * C;
  };
  tset(0, wl1, bn4_g, WL1T, 512, 2048);
  tset(1, wl2, bn5_g, WL2T, 256, 512);
  tset(2, wl3, nullptr, WL3T, 49, 256);
  ta.total = tt;

  hipLaunchKernelGGL(prep_scale_bf16, dim3((sa.total + 255) / 256), dim3(256), 0, stream, sa);
  hipLaunchKernelGGL(prep_w1s_bf16, dim3(104, 2), dim3(256), 0, stream,
                     m1_w1, m1_ws, m1_go, m1_gs, m2_w1, m2_ws, m2_go, m2_gs, M1W1S, M2W1S);
  hipLaunchKernelGGL(prep_transpose_f32, dim3((ta.total + 255) / 256), dim3(256), 0, stream, ta);

  hipLaunchKernelGGL(knn_kernel, dim3(2048), dim3(256), 0, stream, x, IDX);

  // mak1: UV -> fused GEMM2/3 (2 pts/wave, 1024 blocks)
  hipLaunchKernelGGL(mak1_uv, dim3((BB * NN * 64 + 255) / 256), dim3(256), 0, stream,
                     x, m1_w0, m1_g0, m1_b0, MUV);
  hipLaunchKernelGGL(mak23_mfma, dim3(128, 1, BB), dim3(256), 0, stream,
                     x, IDX, MUV, M1WM, m1_bm, M1W1S, m1_bo, m1_bs, X1P);

  // mak2: UV (dense MFMA) -> fused GEMM2/3
  hipLaunchKernelGGL((dense_uv<64, 128>), dim3(8, 1, BB), dim3(256), 0, stream, X1P, M2W0S, m2_b0, MUV);
  hipLaunchKernelGGL(mak23_mfma, dim3(128, 1, BB), dim3(256), 0, stream,
                     x, IDX, MUV, M2WM, m2_bm, M2W1S, m2_bo, m2_bs, X2P);

  // conv3 / conv4: dense UV then gather-max
  hipLaunchKernelGGL((dense_uv<64, 256>), dim3(16, 1, BB), dim3(256), 0, stream, X2P, W3S, b3, UV3);
  hipLaunchKernelGGL((gather_max<128>), dim3(1024), dim3(256), 0, stream, UV3, IDX, X3P);
  hipLaunchKernelGGL((dense_uv<128, 512>), dim3(16, 2, BB), dim3(256), 0, stream, X3P, W4S, b4, UV4);
  hipLaunchKernelGGL((gather_max<256>), dim3(2048), dim3(256), 0, stream, UV4, IDX, X4P);

  hipLaunchKernelGGL(conv5_mfma, dim3(16, 4, BB), dim3(256), 0, stream,
                     X1P, X2P, X3P, X4P, W5B, b5, PMAX, PSUM);
  hipLaunchKernelGGL(reduce5, dim3(32), dim3(256), 0, stream, PMAX, PSUM, XPg);

  hipLaunchKernelGGL(fc1_kernel, dim3(8, BB), dim3(256), 0, stream, XPg, WL1T, bn4_b, XF1);
  hipLaunchKernelGGL(fc2_kernel, dim3(4, BB), dim3(256), 0, stream, XF1, WL2T, bl2, bn5_g, bn5_b, XF2);
  hipLaunchKernelGGL(fc3_kernel, dim3(1, BB), dim3(256), 0, stream, XF2, WL3T, bl3, (float*)d_out);
}

// Round 15
// 388.545 us; speedup vs baseline: 1.0008x; 1.0008x over previous
//
#include <hip/hip_runtime.h>
#include <math.h>

#define BB 8
#define NN 1024
#define KK 16
#define NKP (NN*KK)
#define BN_INV 0.99999500003749981f

typedef unsigned short u16;
typedef __attribute__((ext_vector_type(8))) short short8;
typedef __attribute__((ext_vector_type(4))) float f32x4;

#define MFMA16(a,b,c) __builtin_amdgcn_mfma_f32_16x16x32_bf16(a,b,c,0,0,0)

__device__ __forceinline__ float lrelu(float v) { return v >= 0.f ? v : 0.2f * v; }

__device__ __forceinline__ u16 f2bf(float f) {
  union { float f; unsigned u; } v; v.f = f;
  unsigned r = v.u + 0x7fff + ((v.u >> 16) & 1);
  return (u16)(r >> 16);
}
__device__ __forceinline__ float bf2f(u16 s) {
  union { unsigned u; float f; } v; v.u = ((unsigned)s) << 16;
  return v.f;
}

// ---------------- workspace byte offsets ----------------
constexpr size_t OFF_IDX   = 0;          // int[8*1024*16]
constexpr size_t OFF_X1P   = 524288;     // bf16 [8][1024][64]
constexpr size_t OFF_X2P   = 1572864;
constexpr size_t OFF_X3P   = 2621440;    // bf16 [8][1024][128]  (aliased as MUV during mak)
constexpr size_t OFF_MUV   = 2621440;    // bf16 [8][1024][128] u|v
constexpr size_t OFF_X4P   = 4718592;    // bf16 [8][1024][256]
constexpr size_t OFF_PMAX  = 8912896;    // f32 [8][16][1024]
constexpr size_t OFF_PSUM  = 9437184;
constexpr size_t OFF_XF1   = 10027008;   // f32 [8][512]
constexpr size_t OFF_M1WM  = 10055680;   // bf16 [2][64][32]
constexpr size_t OFF_M1W1S = 10063872;   // bf16 [13][64][32]
constexpr size_t OFF_M2W0S = 10117120;   // bf16 [2][128][32] stacked [Wd;Wc-Wd]
constexpr size_t OFF_M2WM  = 10133504;   // bf16 [2][64][32]
constexpr size_t OFF_M2W1S = 10141696;   // bf16 [13][64][32]
constexpr size_t OFF_W3S   = 10194944;   // bf16 [2][256][32] stacked
constexpr size_t OFF_W4S   = 10227712;   // bf16 [4][512][32] stacked
constexpr size_t OFF_W5    = 10358784;   // bf16 [16][1024][32]
constexpr size_t OFF_WL1T  = 11407360;   // f32 [2048][512]
constexpr size_t OFF_WL2T  = 15601664;   // f32 [512][256]
constexpr size_t OFF_WL3T  = 16125952;   // f32 [256][49]
constexpr size_t OFF_UV3   = 16177152;   // bf16 [8][1024][256] conv3 u|v
constexpr size_t OFF_UV4   = 20371456;   // bf16 [8][1024][512] conv4 u|v

// ---------------- merged weight prep (3-in-1) ----------------
struct SSeg { const float* w; const float* g; u16* dst; int O; int C; int cpl2; int ch; int stk; int start; };
struct SArgs { SSeg seg[6]; int total; };
struct TSeg { const float* w; const float* g; float* dst; int O; int C; int start; };
struct TArgs3 { TSeg seg[3]; int total; };
struct PrepAll {
  SArgs sa;
  const float *w1a, *wsa, *goa, *gsa, *w1b, *wsb, *gob, *gsb;
  u16 *dsta, *dstb;
  TArgs3 ta;
  int nA, nB;
};

__global__ __launch_bounds__(256) void prep_all(PrepAll P) {
  const int bx = blockIdx.x;
  const int t = threadIdx.x;
  if (bx < P.nA) {
    const int tid = bx * 256 + t;
    if (tid >= P.sa.total) return;
    int s = 0;
    #pragma unroll
    for (int i = 1; i < 6; ++i) if (tid >= P.sa.seg[i].start) s = i;
    const SSeg sg = P.sa.seg[s];
    const int e = tid - sg.start;
    const int o2 = e >> sg.cpl2;
    const int c = e & ((1 << sg.cpl2) - 1);
    float v = 0.f;
    if (sg.stk) {
      const int half = sg.O >> 1;
      const int o = o2 & (half - 1);
      const int CIN = 2 * sg.C;
      const float wd = sg.w[o * CIN + c];
      v = (o2 < half) ? wd : (sg.w[o * CIN + sg.C + c] - wd);
      v *= sg.g[o] * BN_INV;
    } else if (c < sg.C) {
      v = sg.w[o2 * sg.C + c];
      if (sg.ch && c >= sg.ch) v -= sg.w[o2 * sg.C + c - sg.ch];
      v *= sg.g[o2] * BN_INV;
    }
    sg.dst[(size_t)(c >> 5) * (sg.O * 32) + o2 * 32 + (c & 31)] = f2bf(v);
  } else if (bx < P.nA + P.nB) {
    const int tid = (bx - P.nA) * 256 + t;     // 2 sets of 64*416 = 26624
    const int set = (tid >= 26624) ? 1 : 0;
    const int id2 = tid - set * 26624;
    const float* w1 = set ? P.w1b : P.w1a;
    const float* wsm = set ? P.wsb : P.wsa;
    const float* go = set ? P.gob : P.goa;
    const float* gs = set ? P.gsb : P.gsa;
    u16* dst = set ? P.dstb : P.dsta;
    const int o = id2 / 416, ci = id2 - o * 416;
    float v = 0.f;
    if (ci < 384) {
      const int ii = ci >> 6, ch = ci & 63;
      const int base = (o * 24 + ii * 4) * 64 + ch;
      v = go[o] * BN_INV * (w1[base] + w1[base + 64] + w1[base + 128] + w1[base + 192]);
    } else if (ci < 390) {
      v = gs[o] * BN_INV * wsm[o * 6 + (ci - 384)];
    }
    dst[(size_t)(ci >> 5) * 2048 + o * 32 + (ci & 31)] = f2bf(v);
  } else {
    const int tid = (bx - P.nA - P.nB) * 256 + t;
    if (tid >= P.ta.total) return;
    int s = 0;
    #pragma unroll
    for (int i = 1; i < 3; ++i) if (tid >= P.ta.seg[i].start) s = i;
    const TSeg sg = P.ta.seg[s];
    const int e = tid - sg.start;
    const int c = e / sg.O;
    const int o = e - c * sg.O;
    float v = sg.w[o * sg.C + c];
    if (sg.g) v *= sg.g[o] * BN_INV;
    sg.dst[e] = v;
  }
}

// ---------------- KNN + mak1_uv merged (both independent, read only x) ----------------
__global__ __launch_bounds__(256) void knn_mak1uv(
    const float* __restrict__ x, int* __restrict__ idxout,
    const float* __restrict__ w0, const float* __restrict__ g0,
    const float* __restrict__ b0, u16* __restrict__ MUV) {
  if (blockIdx.x < 2048) {
    // ---- KNN (exact fp32) ----
    const int wid  = (blockIdx.x * blockDim.x + threadIdx.x) >> 6;
    const int lane = threadIdx.x & 63;
    const int b = wid >> 10;
    const int n = wid & (NN - 1);
    const float* xb = x + b * 3 * NN;
    const float x0n = xb[n], x1n = xb[NN + n], x2n = xb[2 * NN + n];
    const float xxn = x0n * x0n + x1n * x1n + x2n * x2n;
    float pd[16];
    #pragma unroll
    for (int j = 0; j < 16; ++j) {
      const int m = j * 64 + lane;
      const float x0 = xb[m], x1 = xb[NN + m], x2 = xb[2 * NN + m];
      const float dot = x0n * x0 + x1n * x1 + x2n * x2;
      const float xxm = x0 * x0 + x1 * x1 + x2 * x2;
      pd[j] = 2.f * dot - xxn - xxm;
    }
    for (int r = 0; r < 16; ++r) {
      float bv = pd[0]; int bj = 0;
      #pragma unroll
      for (int j = 1; j < 16; ++j) if (pd[j] > bv) { bv = pd[j]; bj = j; }
      int bm = bj * 64 + lane;
      #pragma unroll
      for (int off = 32; off > 0; off >>= 1) {
        const float ov = __shfl_down(bv, off);
        const int   om = __shfl_down(bm, off);
        if (ov > bv || (ov == bv && om < bm)) { bv = ov; bm = om; }
      }
      bm = __shfl(bm, 0);
      if (lane == 0) idxout[wid * KK + r] = bm;
      const int  cj   = bm >> 6;
      const bool mine = (bm & 63) == lane;
      #pragma unroll
      for (int j = 0; j < 16; ++j) if (mine && j == cj) pd[j] = -INFINITY;
    }
  } else {
    // ---- mak1 UV: U=g*Wd*coord, V=g*(Wc-Wd)*coord+b0 ----
    const int tid = (blockIdx.x - 2048) * 256 + threadIdx.x;
    if (tid >= BB * NN * 64) return;
    const int o = tid & 63;
    const int p = tid >> 6;
    const int b = p >> 10, n = p & (NN - 1);
    const float* xb = x + b * 3 * NN;
    const float gg = g0[o] * BN_INV;
    float u = 0.f, v = 0.f;
    #pragma unroll
    for (int i = 0; i < 3; ++i) {
      const float wd = w0[o * 6 + i];
      const float wc = w0[o * 6 + 3 + i];
      const float c = xb[i * NN + n];
      u += wd * c;
      v += (wc - wd) * c;
    }
    MUV[(size_t)p * 128 + o]      = f2bf(gg * u);
    MUV[(size_t)p * 128 + 64 + o] = f2bf(gg * v + b0[o]);
  }
}

// ---------------- helpers ----------------
__device__ __forceinline__ short8 bfrag64(const u16* T, int pl, int quad, int c0) {
  const int pos = ((c0 >> 3) + quad) ^ (pl & 7);
  return *(const short8*)(T + pl * 64 + pos * 8);
}
__device__ __forceinline__ void writeD64(u16* T, int pl, int quad, const f32x4 a,
                                         const float* __restrict__ bias, int obase) {
  union { ushort4 v; u16 s[4]; } pk;
  #pragma unroll
  for (int r = 0; r < 4; ++r) pk.s[r] = f2bf(lrelu(a[r] + bias[obase + quad * 4 + r]));
  const int g = (obase + quad * 4) >> 3;
  const int pos = g ^ (pl & 7);
  *(ushort4*)(T + pl * 64 + pos * 8 + (quad & 1) * 4) = pk.v;
}

// ---------------- mak23 fused: 2 points/wave (R14 variant) ----------------
__global__ __launch_bounds__(256) void mak23_mfma(
    const float* __restrict__ x, const int* __restrict__ idxb, const u16* __restrict__ MUV,
    const u16* __restrict__ wmb, const float* __restrict__ bmv,
    const u16* __restrict__ w1s, const float* __restrict__ bov, const float* __restrict__ bsv,
    u16* __restrict__ Xoutp) {
  __shared__ __align__(16) u16 YMs[4][32 * 64];

  const int t = threadIdx.x;
  const int b = blockIdx.z;
  const int w = t >> 6, l = t & 63;
  const int quad = l >> 4, l15 = l & 15;
  const int cq8 = quad * 8;
  const int p0 = blockIdx.x * 8 + w * 2;
  u16* myYM = YMs[w];
  const float* xb = x + b * 3 * NN;

  int nbr[2];
  #pragma unroll
  for (int pg = 0; pg < 2; ++pg)
    nbr[pg] = idxb[(size_t)(b * NN + p0 + pg) * 16 + l15] & (NN - 1);

  float ge[2][6];
  short8 bgv[2];
  #pragma unroll
  for (int pg = 0; pg < 2; ++pg) {
    const int ctr = p0 + pg;
    union { short8 v; u16 s[8]; } gq;
    gq.v = (short8)(short)0;
    #pragma unroll
    for (int i = 0; i < 3; ++i) {
      const float fc = xb[i * NN + ctr];
      ge[pg][i]     = xb[i * NN + nbr[pg]] - fc;
      ge[pg][3 + i] = fc;
      gq.s[i]     = f2bf(ge[pg][i]);
      gq.s[3 + i] = f2bf(ge[pg][3 + i]);
    }
    bgv[pg] = (quad == 0) ? gq.v : (short8)(short)0;
  }

  short8 bf[2][2];
  #pragma unroll
  for (int pg = 0; pg < 2; ++pg) {
    const u16* urow = MUV + (size_t)(b * NN + nbr[pg]) * 128;
    const u16* vrow = MUV + (size_t)(b * NN + p0 + pg) * 128 + 64;
    #pragma unroll
    for (int kc = 0; kc < 2; ++kc) {
      union { short8 v; u16 s[8]; } uu, vv, rr;
      uu.v = *(const short8*)(urow + kc * 32 + cq8);
      vv.v = *(const short8*)(vrow + kc * 32 + cq8);
      #pragma unroll
      for (int j = 0; j < 8; ++j) rr.s[j] = f2bf(lrelu(bf2f(uu.s[j]) + bf2f(vv.s[j])));
      bf[pg][kc] = rr.v;
    }
  }

  // ---- GEMM2 ----
  #pragma unroll
  for (int at = 0; at < 4; ++at) {
    f32x4 a2[2];
    #pragma unroll
    for (int pg = 0; pg < 2; ++pg) a2[pg] = (f32x4)0.f;
    #pragma unroll
    for (int kc = 0; kc < 2; ++kc) {
      const short8 af = *(const short8*)(wmb + (size_t)(kc * 64 + at * 16 + l15) * 32 + cq8);
      #pragma unroll
      for (int pg = 0; pg < 2; ++pg) a2[pg] = MFMA16(af, bf[pg][kc], a2[pg]);
    }
    #pragma unroll
    for (int pg = 0; pg < 2; ++pg) writeD64(myYM, pg * 16 + l15, quad, a2[pg], bmv, at * 16);
  }

  // ---- GEMM3 ----
  short8 bf3[2][2];
  #pragma unroll
  for (int pg = 0; pg < 2; ++pg)
    #pragma unroll
    for (int kc = 0; kc < 2; ++kc)
      bf3[pg][kc] = bfrag64(myYM, pg * 16 + l15, quad, kc * 32);

  f32x4 acc[2][4];
  #pragma unroll
  for (int pg = 0; pg < 2; ++pg)
    #pragma unroll
    for (int at = 0; at < 4; ++at) acc[pg][at] = (f32x4)0.f;

  #pragma unroll
  for (int ii = 0; ii < 6; ++ii) {
    f32x4 tac[2][4];
    #pragma unroll
    for (int pg = 0; pg < 2; ++pg)
      #pragma unroll
      for (int at = 0; at < 4; ++at) tac[pg][at] = (f32x4)0.f;
    #pragma unroll
    for (int kc = 0; kc < 2; ++kc) {
      #pragma unroll
      for (int at = 0; at < 4; ++at) {
        const short8 af = *(const short8*)(w1s + (size_t)((ii * 2 + kc) * 64 + at * 16 + l15) * 32 + cq8);
        #pragma unroll
        for (int pg = 0; pg < 2; ++pg) tac[pg][at] = MFMA16(af, bf3[pg][kc], tac[pg][at]);
      }
    }
    #pragma unroll
    for (int pg = 0; pg < 2; ++pg) {
      const float g = ge[pg][ii];
      #pragma unroll
      for (int at = 0; at < 4; ++at) acc[pg][at] += g * tac[pg][at];
    }
  }
  #pragma unroll
  for (int at = 0; at < 4; ++at) {
    const short8 af = *(const short8*)(w1s + (size_t)(12 * 64 + at * 16 + l15) * 32 + cq8);
    #pragma unroll
    for (int pg = 0; pg < 2; ++pg) acc[pg][at] = MFMA16(af, bgv[pg], acc[pg][at]);
  }

  #pragma unroll
  for (int pg = 0; pg < 2; ++pg) {
    u16* orow = Xoutp + (size_t)(b * NN + p0 + pg) * 64;
    #pragma unroll
    for (int at = 0; at < 4; ++at) {
      union { ushort4 v; u16 s[4]; } pk;
      #pragma unroll
      for (int r = 0; r < 4; ++r) {
        const int o = at * 16 + quad * 4 + r;
        float v = lrelu(acc[pg][at][r] + bov[o] + bsv[o]);
        v = fmaxf(v, __shfl_xor(v, 1));
        v = fmaxf(v, __shfl_xor(v, 2));
        v = fmaxf(v, __shfl_xor(v, 4));
        v = fmaxf(v, __shfl_xor(v, 8));
        pk.s[r] = f2bf(v);
      }
      if (l15 == 0) *(ushort4*)(orow + at * 16 + quad * 4) = pk.v;
    }
  }
}

// ---------------- dense UV GEMM ----------------
template<int CH, int COUT2>
__global__ __launch_bounds__(256) void dense_uv(
    const u16* __restrict__ srcp, const u16* __restrict__ w2,
    const float* __restrict__ bias, u16* __restrict__ UV) {
  constexpr int COUT = COUT2 / 2;
  constexpr int NCH = CH / 32;
  const int t = threadIdx.x;
  const int b = blockIdx.z;
  const int w = t >> 6, l = t & 63;
  const int quad = l >> 4, l15 = l & 15;
  const int cq8 = quad * 8;
  int n0, ow0;
  if constexpr (COUT2 >= 256) { n0 = blockIdx.x * 64; ow0 = blockIdx.y * 256 + w * 64; }
  else { n0 = blockIdx.x * 128 + (w >> 1) * 64; ow0 = (w & 1) * 64; }

  f32x4 acc[4][4];
  #pragma unroll
  for (int i = 0; i < 4; ++i)
    #pragma unroll
    for (int j = 0; j < 4; ++j) acc[i][j] = (f32x4)0.f;

  #pragma unroll
  for (int k = 0; k < NCH; ++k) {
    short8 bfr[4];
    #pragma unroll
    for (int pg = 0; pg < 4; ++pg) {
      const int n = n0 + pg * 16 + l15;
      bfr[pg] = *(const short8*)(srcp + (size_t)(b * NN + n) * CH + k * 32 + cq8);
    }
    #pragma unroll
    for (int at = 0; at < 4; ++at) {
      const short8 af = *(const short8*)(w2 + ((size_t)(k * COUT2 + ow0 + at * 16 + l15)) * 32 + cq8);
      #pragma unroll
      for (int pg = 0; pg < 4; ++pg) acc[at][pg] = MFMA16(af, bfr[pg], acc[at][pg]);
    }
  }

  #pragma unroll
  for (int at = 0; at < 4; ++at) {
    const int o0 = ow0 + at * 16 + quad * 4;
    const bool isv = (o0 >= COUT);
    float bb[4];
    #pragma unroll
    for (int r = 0; r < 4; ++r) bb[r] = isv ? bias[o0 + r - COUT] : 0.f;
    #pragma unroll
    for (int pg = 0; pg < 4; ++pg) {
      const int n = n0 + pg * 16 + l15;
      union { ushort4 v; u16 s[4]; } pk;
      #pragma unroll
      for (int r = 0; r < 4; ++r) pk.s[r] = f2bf(acc[at][pg][r] + bb[r]);
      *(ushort4*)(UV + (size_t)(b * NN + n) * COUT2 + o0) = pk.v;
    }
  }
}

// ---------------- gather-max ----------------
__device__ __forceinline__ float4 ubf4(ushort4 q) {
  float4 f;
  f.x = bf2f(q.x); f.y = bf2f(q.y); f.z = bf2f(q.z); f.w = bf2f(q.w);
  return f;
}

template<int COUT>
__global__ __launch_bounds__(256) void gather_max(
    const u16* __restrict__ UV, const int* __restrict__ idxb,
    u16* __restrict__ Xoutp) {
  constexpr int CG = COUT / 4;
  const int tid = blockIdx.x * 256 + threadIdx.x;
  const int cg = tid & (CG - 1);
  const int P = tid / CG;
  const int b = P >> 10;
  const int n = P & (NN - 1);

  const float4 vv = ubf4(*(const ushort4*)(UV + (size_t)P * (2 * COUT) + COUT + 4 * cg));
  const int4* ip = (const int4*)(idxb + (size_t)b * NKP + n * 16);
  float4 m = {-INFINITY, -INFINITY, -INFINITY, -INFINITY};
  #pragma unroll
  for (int kq = 0; kq < 4; ++kq) {
    const int4 iv = ip[kq];
    const int mr[4] = { iv.x & (NN - 1), iv.y & (NN - 1), iv.z & (NN - 1), iv.w & (NN - 1) };
    ushort4 uq[4];
    #pragma unroll
    for (int j = 0; j < 4; ++j)
      uq[j] = *(const ushort4*)(UV + (size_t)(b * NN + mr[j]) * (2 * COUT) + 4 * cg);
    #pragma unroll
    for (int j = 0; j < 4; ++j) {
      const float4 uu = ubf4(uq[j]);
      float4 s;
      s.x = uu.x + vv.x; s.y = uu.y + vv.y; s.z = uu.z + vv.z; s.w = uu.w + vv.w;
      m.x = fmaxf(m.x, fmaxf(s.x, 0.2f * s.x));
      m.y = fmaxf(m.y, fmaxf(s.y, 0.2f * s.y));
      m.z = fmaxf(m.z, fmaxf(s.z, 0.2f * s.z));
      m.w = fmaxf(m.w, fmaxf(s.w, 0.2f * s.w));
    }
  }
  union { ushort4 v; u16 s[4]; } pk;
  pk.s[0] = f2bf(m.x); pk.s[1] = f2bf(m.y); pk.s[2] = f2bf(m.z); pk.s[3] = f2bf(m.w);
  *(ushort4*)(Xoutp + (size_t)P * COUT + 4 * cg) = pk.v;
}

// ---------------- conv5 ----------------
__global__ __launch_bounds__(256) void conv5_mfma(
    const u16* __restrict__ X1P, const u16* __restrict__ X2P,
    const u16* __restrict__ X3P, const u16* __restrict__ X4P,
    const u16* __restrict__ w5b, const float* __restrict__ b5,
    float* __restrict__ PMAX, float* __restrict__ PSUM) {
  const int t = threadIdx.x;
  const int b = blockIdx.z;
  const int n0 = blockIdx.x * 64;
  const int w = t >> 6, l = t & 63;
  const int quad = l >> 4, l15 = l & 15;
  const int cq8 = quad * 8;
  const int ow0 = blockIdx.y * 256 + w * 64;

  f32x4 acc[4][4];
  #pragma unroll
  for (int i = 0; i < 4; ++i)
    #pragma unroll
    for (int j = 0; j < 4; ++j) acc[i][j] = (f32x4)0.f;

  #pragma unroll 4
  for (int k = 0; k < 16; ++k) {
    const int c = k * 32 + cq8;
    short8 bfr[4];
    #pragma unroll
    for (int pg = 0; pg < 4; ++pg) {
      const int n = n0 + pg * 16 + l15;
      const u16* src; int cc;
      if (c < 64)       { src = X1P + (size_t)(b * NN + n) * 64;  cc = c; }
      else if (c < 128) { src = X2P + (size_t)(b * NN + n) * 64;  cc = c - 64; }
      else if (c < 256) { src = X3P + (size_t)(b * NN + n) * 128; cc = c - 128; }
      else              { src = X4P + (size_t)(b * NN + n) * 256; cc = c - 256; }
      bfr[pg] = *(const short8*)(src + cc);
    }
    #pragma unroll
    for (int at = 0; at < 4; ++at) {
      const short8 af = *(const short8*)(w5b + ((size_t)(k * 1024 + ow0 + at * 16 + l15)) * 32 + cq8);
      #pragma unroll
      for (int pg = 0; pg < 4; ++pg) acc[at][pg] = MFMA16(af, bfr[pg], acc[at][pg]);
    }
  }

  #pragma unroll
  for (int at = 0; at < 4; ++at) {
    f32x4 pmx, psm;
    #pragma unroll
    for (int r = 0; r < 4; ++r) {
      const float bb = b5[ow0 + at * 16 + quad * 4 + r];
      float m = -INFINITY, s = 0.f;
      #pragma unroll
      for (int pg = 0; pg < 4; ++pg) {
        const float v = lrelu(acc[at][pg][r] + bb);
        m = fmaxf(m, v); s += v;
      }
      #pragma unroll
      for (int msk = 1; msk < 16; msk <<= 1) {
        m = fmaxf(m, __shfl_xor(m, msk));
        s += __shfl_xor(s, msk);
      }
      pmx[r] = m; psm[r] = s;
    }
    if (l15 == 0) {
      float* dm = PMAX + (size_t)(b * 16 + blockIdx.x) * 1024 + ow0 + at * 16 + quad * 4;
      float* ds = PSUM + (size_t)(b * 16 + blockIdx.x) * 1024 + ow0 + at * 16 + quad * 4;
      *(f32x4*)dm = pmx;
      *(f32x4*)ds = psm;
    }
  }
}

// ---------------- fc1 (inlined reduce: builds xp in LDS from PMAX/PSUM) ----------------
__global__ __launch_bounds__(256) void fc1_kernel(
    const float* __restrict__ PMAX, const float* __restrict__ PSUM,
    const float* __restrict__ wl1t, const float* __restrict__ bn4_b,
    float* __restrict__ XF1) {
  __shared__ float xp[2048];
  __shared__ float red[64 * 5];
  const int t = threadIdx.x;
  const int b = blockIdx.y;
  // stage xp[0..1023]=max, xp[1024..2047]=mean
  for (int e = t; e < 1024; e += 256) {
    float m = -INFINITY, s = 0.f;
    #pragma unroll 4
    for (int pt = 0; pt < 16; ++pt) {
      m = fmaxf(m, PMAX[(size_t)(b * 16 + pt) * 1024 + e]);
      s += PSUM[(size_t)(b * 16 + pt) * 1024 + e];
    }
    xp[e] = m;
    xp[1024 + e] = s * (1.f / 1024.f);
  }
  __syncthreads();
  const int o = blockIdx.x * 64 + (t & 63);
  const int cq = t >> 6;
  float acc = 0.f;
  for (int c = cq * 512; c < cq * 512 + 512; ++c) acc = fmaf(wl1t[c * 512 + o], xp[c], acc);
  red[(t & 63) * 5 + cq] = acc;
  __syncthreads();
  if (t < 64) {
    const int oo = blockIdx.x * 64 + t;
    const float v = red[t * 5] + red[t * 5 + 1] + red[t * 5 + 2] + red[t * 5 + 3] + bn4_b[oo];
    XF1[b * 512 + oo] = lrelu(v);
  }
}

// ---------------- fc2 + fc3 merged (one block per batch) ----------------
__global__ __launch_bounds__(256) void fc23_kernel(
    const float* __restrict__ XF1, const float* __restrict__ wl2t,
    const float* __restrict__ bl2, const float* __restrict__ bn5_g,
    const float* __restrict__ bn5_b, const float* __restrict__ wl3t,
    const float* __restrict__ bl3, float* __restrict__ out) {
  __shared__ float xf1s[512];
  __shared__ float xf2s[256];
  const int t = threadIdx.x;
  const int b = blockIdx.x;
  for (int e = t; e < 512; e += 256) xf1s[e] = XF1[b * 512 + e];
  __syncthreads();
  {
    // fc2: thread t computes output o=t (256 outs, 512 inputs)
    float acc = 0.f;
    #pragma unroll 8
    for (int c = 0; c < 512; ++c) acc = fmaf(wl2t[c * 256 + t], xf1s[c], acc);
    const float bias = bl2[t] * (bn5_g[t] * BN_INV) + bn5_b[t];
    xf2s[t] = lrelu(acc + bias);
  }
  __syncthreads();
  if (t < 49) {
    float acc = 0.f;
    #pragma unroll 8
    for (int c = 0; c < 256; ++c) acc = fmaf(wl3t[c * 49 + t], xf2s[c], acc);
    out[b * 49 + t] = acc + bl3[t];
  }
}

// ---------------- host ----------------
extern "C" void kernel_launch(void* const* d_in, const int* in_sizes, int n_in,
                              void* d_out, int out_size, void* d_ws, size_t ws_size,
                              hipStream_t stream) {
  (void)in_sizes; (void)n_in; (void)out_size; (void)ws_size;
  const float* x     = (const float*)d_in[0];
  const float* m1_w0 = (const float*)d_in[1];
  const float* m1_g0 = (const float*)d_in[2];
  const float* m1_b0 = (const float*)d_in[3];
  const float* m1_wm = (const float*)d_in[4];
  const float* m1_gm = (const float*)d_in[5];
  const float* m1_bm = (const float*)d_in[6];
  const float* m1_w1 = (const float*)d_in[7];
  const float* m1_go = (const float*)d_in[8];
  const float* m1_bo = (const float*)d_in[9];
  const float* m1_ws = (const float*)d_in[10];
  const float* m1_gs = (const float*)d_in[11];
  const float* m1_bs = (const float*)d_in[12];
  const float* m2_w0 = (const float*)d_in[13];
  const float* m2_g0 = (const float*)d_in[14];
  const float* m2_b0 = (const float*)d_in[15];
  const float* m2_wm = (const float*)d_in[16];
  const float* m2_gm = (const float*)d_in[17];
  const float* m2_bm = (const float*)d_in[18];
  const float* m2_w1 = (const float*)d_in[19];
  const float* m2_go = (const float*)d_in[20];
  const float* m2_bo = (const float*)d_in[21];
  const float* m2_ws = (const float*)d_in[22];
  const float* m2_gs = (const float*)d_in[23];
  const float* m2_bs = (const float*)d_in[24];
  const float* w3    = (const float*)d_in[25];
  const float* g3    = (const float*)d_in[26];
  const float* b3    = (const float*)d_in[27];
  const float* w4    = (const float*)d_in[28];
  const float* g4    = (const float*)d_in[29];
  const float* b4    = (const float*)d_in[30];
  const float* w5    = (const float*)d_in[31];
  const float* g5    = (const float*)d_in[32];
  const float* b5    = (const float*)d_in[33];
  const float* wl1   = (const float*)d_in[34];
  const float* bn4_g = (const float*)d_in[35];
  const float* bn4_b = (const float*)d_in[36];
  const float* wl2   = (const float*)d_in[37];
  const float* bl2   = (const float*)d_in[38];
  const float* bn5_g = (const float*)d_in[39];
  const float* bn5_b = (const float*)d_in[40];
  const float* wl3   = (const float*)d_in[41];
  const float* bl3   = (const float*)d_in[42];

  char* wsb = (char*)d_ws;
  int*  IDX  = (int*)(wsb + OFF_IDX);
  u16*  X1P  = (u16*)(wsb + OFF_X1P);
  u16*  X2P  = (u16*)(wsb + OFF_X2P);
  u16*  X3P  = (u16*)(wsb + OFF_X3P);
  u16*  X4P  = (u16*)(wsb + OFF_X4P);
  u16*  MUV  = (u16*)(wsb + OFF_MUV);
  float* PMAX = (float*)(wsb + OFF_PMAX);
  float* PSUM = (float*)(wsb + OFF_PSUM);
  float* XF1  = (float*)(wsb + OFF_XF1);
  u16*  M1WM = (u16*)(wsb + OFF_M1WM);
  u16*  M1W1S = (u16*)(wsb + OFF_M1W1S);
  u16*  M2W0S = (u16*)(wsb + OFF_M2W0S);
  u16*  M2WM = (u16*)(wsb + OFF_M2WM);
  u16*  M2W1S = (u16*)(wsb + OFF_M2W1S);
  u16*  W3S  = (u16*)(wsb + OFF_W3S);
  u16*  W4S  = (u16*)(wsb + OFF_W4S);
  u16*  W5B  = (u16*)(wsb + OFF_W5);
  float* WL1T = (float*)(wsb + OFF_WL1T);
  float* WL2T = (float*)(wsb + OFF_WL2T);
  float* WL3T = (float*)(wsb + OFF_WL3T);
  u16*  UV3  = (u16*)(wsb + OFF_UV3);
  u16*  UV4  = (u16*)(wsb + OFF_UV4);

  PrepAll P;
  int st = 0;
  auto sset = [&](int i, const float* w, const float* g, u16* dst, int O, int C, int cpl2, int ch, int stk) {
    P.sa.seg[i].w = w; P.sa.seg[i].g = g; P.sa.seg[i].dst = dst; P.sa.seg[i].O = O; P.sa.seg[i].C = C;
    P.sa.seg[i].cpl2 = cpl2; P.sa.seg[i].ch = ch; P.sa.seg[i].stk = stk; P.sa.seg[i].start = st;
    st += O << cpl2;
  };
  sset(0, m1_wm, m1_gm, M1WM, 64, 64, 6, 0, 0);
  sset(1, m2_w0, m2_g0, M2W0S, 128, 64, 6, 0, 1);
  sset(2, m2_wm, m2_gm, M2WM, 64, 64, 6, 0, 0);
  sset(3, w3, g3, W3S, 256, 64, 6, 0, 1);
  sset(4, w4, g4, W4S, 512, 128, 7, 0, 1);
  sset(5, w5, g5, W5B, 1024, 512, 9, 0, 0);
  P.sa.total = st;

  P.w1a = m1_w1; P.wsa = m1_ws; P.goa = m1_go; P.gsa = m1_gs;
  P.w1b = m2_w1; P.wsb = m2_ws; P.gob = m2_go; P.gsb = m2_gs;
  P.dsta = M1W1S; P.dstb = M2W1S;

  int tt = 0;
  auto tset = [&](int i, const float* w, const float* g, float* dst, int O, int C) {
    P.ta.seg[i].w = w; P.ta.seg[i].g = g; P.ta.seg[i].dst = dst; P.ta.seg[i].O = O; P.ta.seg[i].C = C;
    P.ta.seg[i].start = tt; tt += O * C;
  };
  tset(0, wl1, bn4_g, WL1T, 512, 2048);
  tset(1, wl2, bn5_g, WL2T, 256, 512);
  tset(2, wl3, nullptr, WL3T, 49, 256);
  P.ta.total = tt;

  P.nA = (P.sa.total + 255) / 256;          // 2432
  P.nB = (2 * 64 * 416 + 255) / 256;        // 208
  const int nC = (P.ta.total + 255) / 256;  // 4657

  hipLaunchKernelGGL(prep_all, dim3(P.nA + P.nB + nC), dim3(256), 0, stream, P);

  // knn + mak1_uv merged (2048 + 2048 blocks)
  hipLaunchKernelGGL(knn_mak1uv, dim3(4096), dim3(256), 0, stream,
                     x, IDX, m1_w0, m1_g0, m1_b0, MUV);

  hipLaunchKernelGGL(mak23_mfma, dim3(128, 1, BB), dim3(256), 0, stream,
                     x, IDX, MUV, M1WM, m1_bm, M1W1S, m1_bo, m1_bs, X1P);

  hipLaunchKernelGGL((dense_uv<64, 128>), dim3(8, 1, BB), dim3(256), 0, stream, X1P, M2W0S, m2_b0, MUV);
  hipLaunchKernelGGL(mak23_mfma, dim3(128, 1, BB), dim3(256), 0, stream,
                     x, IDX, MUV, M2WM, m2_bm, M2W1S, m2_bo, m2_bs, X2P);

  hipLaunchKernelGGL((dense_uv<64, 256>), dim3(16, 1, BB), dim3(256), 0, stream, X2P, W3S, b3, UV3);
  hipLaunchKernelGGL((gather_max<128>), dim3(1024), dim3(256), 0, stream, UV3, IDX, X3P);
  hipLaunchKernelGGL((dense_uv<128, 512>), dim3(16, 2, BB), dim3(256), 0, stream, X3P, W4S, b4, UV4);
  hipLaunchKernelGGL((gather_max<256>), dim3(2048), dim3(256), 0, stream, UV4, IDX, X4P);

  hipLaunchKernelGGL(conv5_mfma, dim3(16, 4, BB), dim3(256), 0, stream,
                     X1P, X2P, X3P, X4P, W5B, b5, PMAX, PSUM);

  hipLaunchKernelGGL(fc1_kernel, dim3(8, BB), dim3(256), 0, stream, PMAX, PSUM, WL1T, bn4_b, XF1);
  hipLaunchKernelGGL(fc23_kernel, dim3(BB), dim3(256), 0, stream,
                     XF1, WL2T, bl2, bn5_g, bn5_b, WL3T, bl3, (float*)d_out);
}

// Round 16
// 353.171 us; speedup vs baseline: 1.1011x; 1.1002x over previous
//
#include <hip/hip_runtime.h>
#include <math.h>

#define BB 8
#define NN 1024
#define KK 16
#define NKP (NN*KK)
#define BN_INV 0.99999500003749981f

typedef unsigned short u16;
typedef __attribute__((ext_vector_type(8))) short short8;
typedef __attribute__((ext_vector_type(4))) float f32x4;

#define MFMA16(a,b,c) __builtin_amdgcn_mfma_f32_16x16x32_bf16(a,b,c,0,0,0)

__device__ __forceinline__ float lrelu(float v) { return v >= 0.f ? v : 0.2f * v; }

__device__ __forceinline__ u16 f2bf(float f) {
  union { float f; unsigned u; } v; v.f = f;
  unsigned r = v.u + 0x7fff + ((v.u >> 16) & 1);
  return (u16)(r >> 16);
}
__device__ __forceinline__ float bf2f(u16 s) {
  union { unsigned u; float f; } v; v.u = ((unsigned)s) << 16;
  return v.f;
}

// ---------------- workspace byte offsets ----------------
constexpr size_t OFF_IDX   = 0;          // int[8*1024*16]
constexpr size_t OFF_X1P   = 524288;     // bf16 [8][1024][64]
constexpr size_t OFF_X2P   = 1572864;
constexpr size_t OFF_X3P   = 2621440;    // bf16 [8][1024][128]  (aliased as MUV during mak)
constexpr size_t OFF_MUV   = 2621440;    // bf16 [8][1024][128] u|v
constexpr size_t OFF_X4P   = 4718592;    // bf16 [8][1024][256]
constexpr size_t OFF_PMAX  = 8912896;    // f32 [8][16][1024]
constexpr size_t OFF_PSUM  = 9437184;
constexpr size_t OFF_XF1   = 10027008;   // f32 [8][512]
constexpr size_t OFF_M1WM  = 10055680;   // bf16 [2][64][32]
constexpr size_t OFF_M1W1S = 10063872;   // bf16 [13][64][32]
constexpr size_t OFF_M2W0S = 10117120;   // bf16 [2][128][32] stacked [Wd;Wc-Wd]
constexpr size_t OFF_M2WM  = 10133504;   // bf16 [2][64][32]
constexpr size_t OFF_M2W1S = 10141696;   // bf16 [13][64][32]
constexpr size_t OFF_W3S   = 10194944;   // bf16 [2][256][32] stacked
constexpr size_t OFF_W4S   = 10227712;   // bf16 [4][512][32] stacked
constexpr size_t OFF_W5    = 10358784;   // bf16 [16][1024][32]
constexpr size_t OFF_WL1T  = 11407360;   // f32 [2048][512]
constexpr size_t OFF_WL2T  = 15601664;   // f32 [512][256]
constexpr size_t OFF_WL3T  = 16125952;   // f32 [256][49]
constexpr size_t OFF_UV3   = 16177152;   // bf16 [8][1024][256] conv3 u|v
constexpr size_t OFF_UV4   = 20371456;   // bf16 [8][1024][512] conv4 u|v

// ---------------- merged weight prep (3-in-1) ----------------
struct SSeg { const float* w; const float* g; u16* dst; int O; int C; int cpl2; int ch; int stk; int start; };
struct SArgs { SSeg seg[6]; int total; };
struct TSeg { const float* w; const float* g; float* dst; int O; int C; int start; };
struct TArgs3 { TSeg seg[3]; int total; };
struct PrepAll {
  SArgs sa;
  const float *w1a, *wsa, *goa, *gsa, *w1b, *wsb, *gob, *gsb;
  u16 *dsta, *dstb;
  TArgs3 ta;
  int nA, nB;
};

__global__ __launch_bounds__(256) void prep_all(PrepAll P) {
  const int bx = blockIdx.x;
  const int t = threadIdx.x;
  if (bx < P.nA) {
    const int tid = bx * 256 + t;
    if (tid >= P.sa.total) return;
    int s = 0;
    #pragma unroll
    for (int i = 1; i < 6; ++i) if (tid >= P.sa.seg[i].start) s = i;
    const SSeg sg = P.sa.seg[s];
    const int e = tid - sg.start;
    const int o2 = e >> sg.cpl2;
    const int c = e & ((1 << sg.cpl2) - 1);
    float v = 0.f;
    if (sg.stk) {
      const int half = sg.O >> 1;
      const int o = o2 & (half - 1);
      const int CIN = 2 * sg.C;
      const float wd = sg.w[o * CIN + c];
      v = (o2 < half) ? wd : (sg.w[o * CIN + sg.C + c] - wd);
      v *= sg.g[o] * BN_INV;
    } else if (c < sg.C) {
      v = sg.w[o2 * sg.C + c];
      if (sg.ch && c >= sg.ch) v -= sg.w[o2 * sg.C + c - sg.ch];
      v *= sg.g[o2] * BN_INV;
    }
    sg.dst[(size_t)(c >> 5) * (sg.O * 32) + o2 * 32 + (c & 31)] = f2bf(v);
  } else if (bx < P.nA + P.nB) {
    const int tid = (bx - P.nA) * 256 + t;     // 2 sets of 64*416 = 26624
    const int set = (tid >= 26624) ? 1 : 0;
    const int id2 = tid - set * 26624;
    const float* w1 = set ? P.w1b : P.w1a;
    const float* wsm = set ? P.wsb : P.wsa;
    const float* go = set ? P.gob : P.goa;
    const float* gs = set ? P.gsb : P.gsa;
    u16* dst = set ? P.dstb : P.dsta;
    const int o = id2 / 416, ci = id2 - o * 416;
    float v = 0.f;
    if (ci < 384) {
      const int ii = ci >> 6, ch = ci & 63;
      const int base = (o * 24 + ii * 4) * 64 + ch;
      v = go[o] * BN_INV * (w1[base] + w1[base + 64] + w1[base + 128] + w1[base + 192]);
    } else if (ci < 390) {
      v = gs[o] * BN_INV * wsm[o * 6 + (ci - 384)];
    }
    dst[(size_t)(ci >> 5) * 2048 + o * 32 + (ci & 31)] = f2bf(v);
  } else {
    const int tid = (bx - P.nA - P.nB) * 256 + t;
    if (tid >= P.ta.total) return;
    int s = 0;
    #pragma unroll
    for (int i = 1; i < 3; ++i) if (tid >= P.ta.seg[i].start) s = i;
    const TSeg sg = P.ta.seg[s];
    const int e = tid - sg.start;
    const int c = e / sg.O;
    const int o = e - c * sg.O;
    float v = sg.w[o * sg.C + c];
    if (sg.g) v *= sg.g[o] * BN_INV;
    sg.dst[e] = v;
  }
}

// ---------------- KNN + mak1_uv merged ----------------
__global__ __launch_bounds__(256) void knn_mak1uv(
    const float* __restrict__ x, int* __restrict__ idxout,
    const float* __restrict__ w0, const float* __restrict__ g0,
    const float* __restrict__ b0, u16* __restrict__ MUV) {
  if (blockIdx.x < 2048) {
    const int wid  = (blockIdx.x * blockDim.x + threadIdx.x) >> 6;
    const int lane = threadIdx.x & 63;
    const int b = wid >> 10;
    const int n = wid & (NN - 1);
    const float* xb = x + b * 3 * NN;
    const float x0n = xb[n], x1n = xb[NN + n], x2n = xb[2 * NN + n];
    const float xxn = x0n * x0n + x1n * x1n + x2n * x2n;
    float pd[16];
    #pragma unroll
    for (int j = 0; j < 16; ++j) {
      const int m = j * 64 + lane;
      const float x0 = xb[m], x1 = xb[NN + m], x2 = xb[2 * NN + m];
      const float dot = x0n * x0 + x1n * x1 + x2n * x2;
      const float xxm = x0 * x0 + x1 * x1 + x2 * x2;
      pd[j] = 2.f * dot - xxn - xxm;
    }
    for (int r = 0; r < 16; ++r) {
      float bv = pd[0]; int bj = 0;
      #pragma unroll
      for (int j = 1; j < 16; ++j) if (pd[j] > bv) { bv = pd[j]; bj = j; }
      int bm = bj * 64 + lane;
      #pragma unroll
      for (int off = 32; off > 0; off >>= 1) {
        const float ov = __shfl_down(bv, off);
        const int   om = __shfl_down(bm, off);
        if (ov > bv || (ov == bv && om < bm)) { bv = ov; bm = om; }
      }
      bm = __shfl(bm, 0);
      if (lane == 0) idxout[wid * KK + r] = bm;
      const int  cj   = bm >> 6;
      const bool mine = (bm & 63) == lane;
      #pragma unroll
      for (int j = 0; j < 16; ++j) if (mine && j == cj) pd[j] = -INFINITY;
    }
  } else {
    const int tid = (blockIdx.x - 2048) * 256 + threadIdx.x;
    if (tid >= BB * NN * 64) return;
    const int o = tid & 63;
    const int p = tid >> 6;
    const int b = p >> 10, n = p & (NN - 1);
    const float* xb = x + b * 3 * NN;
    const float gg = g0[o] * BN_INV;
    float u = 0.f, v = 0.f;
    #pragma unroll
    for (int i = 0; i < 3; ++i) {
      const float wd = w0[o * 6 + i];
      const float wc = w0[o * 6 + 3 + i];
      const float c = xb[i * NN + n];
      u += wd * c;
      v += (wc - wd) * c;
    }
    MUV[(size_t)p * 128 + o]      = f2bf(gg * u);
    MUV[(size_t)p * 128 + 64 + o] = f2bf(gg * v + b0[o]);
  }
}

// ---------------- helpers ----------------
__device__ __forceinline__ short8 bfrag64(const u16* T, int pl, int quad, int c0) {
  const int pos = ((c0 >> 3) + quad) ^ (pl & 7);
  return *(const short8*)(T + pl * 64 + pos * 8);
}
__device__ __forceinline__ void writeD64(u16* T, int pl, int quad, const f32x4 a,
                                         const float* __restrict__ bias, int obase) {
  union { ushort4 v; u16 s[4]; } pk;
  #pragma unroll
  for (int r = 0; r < 4; ++r) pk.s[r] = f2bf(lrelu(a[r] + bias[obase + quad * 4 + r]));
  const int g = (obase + quad * 4) >> 3;
  const int pos = g ^ (pl & 7);
  *(ushort4*)(T + pl * 64 + pos * 8 + (quad & 1) * 4) = pk.v;
}

// ---------------- mak23 fused: 2 points/wave, w1s cached in LDS ----------------
// w1s LDS layout: [chunk 13][row 64][pos 4 x 8 u16], pos = quad ^ (row & 3)  (<=2-way conflicts)
__global__ __launch_bounds__(256) void mak23_mfma(
    const float* __restrict__ x, const int* __restrict__ idxb, const u16* __restrict__ MUV,
    const u16* __restrict__ wmb, const float* __restrict__ bmv,
    const u16* __restrict__ w1s, const float* __restrict__ bov, const float* __restrict__ bsv,
    u16* __restrict__ Xoutp) {
  __shared__ __align__(16) u16 W1S[13 * 2048];    // 53,248 B
  __shared__ __align__(16) u16 YMs[4][32 * 64];   // 16,384 B

  const int t = threadIdx.x;
  const int b = blockIdx.z;
  const int w = t >> 6, l = t & 63;
  const int quad = l >> 4, l15 = l & 15;
  const int cq8 = quad * 8;
  const int p0 = blockIdx.x * 8 + w * 2;
  u16* myYM = YMs[w];
  const float* xb = x + b * 3 * NN;

  // cooperative w1s load -> LDS (swizzled), 13 x uint4 per thread
  #pragma unroll
  for (int i = 0; i < 13; ++i) {
    const int g16 = i * 256 + t;                // 16B granule index (0..3327)
    const int q = g16 & 3;
    const int row = (g16 >> 2) & 63;
    const int ch = g16 >> 8;
    const uint4 val = *(const uint4*)(w1s + (size_t)g16 * 8);
    *(uint4*)(W1S + ch * 2048 + row * 32 + (q ^ (row & 3)) * 8) = val;
  }

  int nbr[2];
  #pragma unroll
  for (int pg = 0; pg < 2; ++pg)
    nbr[pg] = idxb[(size_t)(b * NN + p0 + pg) * 16 + l15] & (NN - 1);

  float ge[2][6];
  short8 bgv[2];
  #pragma unroll
  for (int pg = 0; pg < 2; ++pg) {
    const int ctr = p0 + pg;
    union { short8 v; u16 s[8]; } gq;
    gq.v = (short8)(short)0;
    #pragma unroll
    for (int i = 0; i < 3; ++i) {
      const float fc = xb[i * NN + ctr];
      ge[pg][i]     = xb[i * NN + nbr[pg]] - fc;
      ge[pg][3 + i] = fc;
      gq.s[i]     = f2bf(ge[pg][i]);
      gq.s[3 + i] = f2bf(ge[pg][3 + i]);
    }
    bgv[pg] = (quad == 0) ? gq.v : (short8)(short)0;
  }

  short8 bf[2][2];
  #pragma unroll
  for (int pg = 0; pg < 2; ++pg) {
    const u16* urow = MUV + (size_t)(b * NN + nbr[pg]) * 128;
    const u16* vrow = MUV + (size_t)(b * NN + p0 + pg) * 128 + 64;
    #pragma unroll
    for (int kc = 0; kc < 2; ++kc) {
      union { short8 v; u16 s[8]; } uu, vv, rr;
      uu.v = *(const short8*)(urow + kc * 32 + cq8);
      vv.v = *(const short8*)(vrow + kc * 32 + cq8);
      #pragma unroll
      for (int j = 0; j < 8; ++j) rr.s[j] = f2bf(lrelu(bf2f(uu.s[j]) + bf2f(vv.s[j])));
      bf[pg][kc] = rr.v;
    }
  }

  // ---- GEMM2 (wm from global; tiny, L1-hot) ----
  #pragma unroll
  for (int at = 0; at < 4; ++at) {
    f32x4 a2[2];
    #pragma unroll
    for (int pg = 0; pg < 2; ++pg) a2[pg] = (f32x4)0.f;
    #pragma unroll
    for (int kc = 0; kc < 2; ++kc) {
      const short8 af = *(const short8*)(wmb + (size_t)(kc * 64 + at * 16 + l15) * 32 + cq8);
      #pragma unroll
      for (int pg = 0; pg < 2; ++pg) a2[pg] = MFMA16(af, bf[pg][kc], a2[pg]);
    }
    #pragma unroll
    for (int pg = 0; pg < 2; ++pg) writeD64(myYM, pg * 16 + l15, quad, a2[pg], bmv, at * 16);
  }

  __syncthreads();   // W1S staging complete before GEMM3 A-reads (also orders nothing else: YM is wave-private)

  // ---- GEMM3: A-frags from LDS ----
  short8 bf3[2][2];
  #pragma unroll
  for (int pg = 0; pg < 2; ++pg)
    #pragma unroll
    for (int kc = 0; kc < 2; ++kc)
      bf3[pg][kc] = bfrag64(myYM, pg * 16 + l15, quad, kc * 32);

  const int arow = l15;   // row within o-tile = at*16 + l15
  f32x4 acc[2][4];
  #pragma unroll
  for (int pg = 0; pg < 2; ++pg)
    #pragma unroll
    for (int at = 0; at < 4; ++at) acc[pg][at] = (f32x4)0.f;

  #pragma unroll
  for (int ii = 0; ii < 6; ++ii) {
    f32x4 tac[2][4];
    #pragma unroll
    for (int pg = 0; pg < 2; ++pg)
      #pragma unroll
      for (int at = 0; at < 4; ++at) tac[pg][at] = (f32x4)0.f;
    #pragma unroll
    for (int kc = 0; kc < 2; ++kc) {
      const int ch = ii * 2 + kc;
      #pragma unroll
      for (int at = 0; at < 4; ++at) {
        const int row = at * 16 + arow;
        const short8 af = *(const short8*)(W1S + ch * 2048 + row * 32 + (quad ^ (row & 3)) * 8);
        #pragma unroll
        for (int pg = 0; pg < 2; ++pg) tac[pg][at] = MFMA16(af, bf3[pg][kc], tac[pg][at]);
      }
    }
    #pragma unroll
    for (int pg = 0; pg < 2; ++pg) {
      const float g = ge[pg][ii];
      #pragma unroll
      for (int at = 0; at < 4; ++at) acc[pg][at] += g * tac[pg][at];
    }
  }
  #pragma unroll
  for (int at = 0; at < 4; ++at) {
    const int row = at * 16 + arow;
    const short8 af = *(const short8*)(W1S + 12 * 2048 + row * 32 + (quad ^ (row & 3)) * 8);
    #pragma unroll
    for (int pg = 0; pg < 2; ++pg) acc[pg][at] = MFMA16(af, bgv[pg], acc[pg][at]);
  }

  #pragma unroll
  for (int pg = 0; pg < 2; ++pg) {
    u16* orow = Xoutp + (size_t)(b * NN + p0 + pg) * 64;
    #pragma unroll
    for (int at = 0; at < 4; ++at) {
      union { ushort4 v; u16 s[4]; } pk;
      #pragma unroll
      for (int r = 0; r < 4; ++r) {
        const int o = at * 16 + quad * 4 + r;
        float v = lrelu(acc[pg][at][r] + bov[o] + bsv[o]);
        v = fmaxf(v, __shfl_xor(v, 1));
        v = fmaxf(v, __shfl_xor(v, 2));
        v = fmaxf(v, __shfl_xor(v, 4));
        v = fmaxf(v, __shfl_xor(v, 8));
        pk.s[r] = f2bf(v);
      }
      if (l15 == 0) *(ushort4*)(orow + at * 16 + quad * 4) = pk.v;
    }
  }
}

// ---------------- dense UV GEMM ----------------
template<int CH, int COUT2>
__global__ __launch_bounds__(256) void dense_uv(
    const u16* __restrict__ srcp, const u16* __restrict__ w2,
    const float* __restrict__ bias, u16* __restrict__ UV) {
  constexpr int COUT = COUT2 / 2;
  constexpr int NCH = CH / 32;
  const int t = threadIdx.x;
  const int b = blockIdx.z;
  const int w = t >> 6, l = t & 63;
  const int quad = l >> 4, l15 = l & 15;
  const int cq8 = quad * 8;
  int n0, ow0;
  if constexpr (COUT2 >= 256) { n0 = blockIdx.x * 64; ow0 = blockIdx.y * 256 + w * 64; }
  else { n0 = blockIdx.x * 128 + (w >> 1) * 64; ow0 = (w & 1) * 64; }

  f32x4 acc[4][4];
  #pragma unroll
  for (int i = 0; i < 4; ++i)
    #pragma unroll
    for (int j = 0; j < 4; ++j) acc[i][j] = (f32x4)0.f;

  #pragma unroll
  for (int k = 0; k < NCH; ++k) {
    short8 bfr[4];
    #pragma unroll
    for (int pg = 0; pg < 4; ++pg) {
      const int n = n0 + pg * 16 + l15;
      bfr[pg] = *(const short8*)(srcp + (size_t)(b * NN + n) * CH + k * 32 + cq8);
    }
    #pragma unroll
    for (int at = 0; at < 4; ++at) {
      const short8 af = *(const short8*)(w2 + ((size_t)(k * COUT2 + ow0 + at * 16 + l15)) * 32 + cq8);
      #pragma unroll
      for (int pg = 0; pg < 4; ++pg) acc[at][pg] = MFMA16(af, bfr[pg], acc[at][pg]);
    }
  }

  #pragma unroll
  for (int at = 0; at < 4; ++at) {
    const int o0 = ow0 + at * 16 + quad * 4;
    const bool isv = (o0 >= COUT);
    float bb[4];
    #pragma unroll
    for (int r = 0; r < 4; ++r) bb[r] = isv ? bias[o0 + r - COUT] : 0.f;
    #pragma unroll
    for (int pg = 0; pg < 4; ++pg) {
      const int n = n0 + pg * 16 + l15;
      union { ushort4 v; u16 s[4]; } pk;
      #pragma unroll
      for (int r = 0; r < 4; ++r) pk.s[r] = f2bf(acc[at][pg][r] + bb[r]);
      *(ushort4*)(UV + (size_t)(b * NN + n) * COUT2 + o0) = pk.v;
    }
  }
}

// ---------------- gather-max ----------------
__device__ __forceinline__ float4 ubf4(ushort4 q) {
  float4 f;
  f.x = bf2f(q.x); f.y = bf2f(q.y); f.z = bf2f(q.z); f.w = bf2f(q.w);
  return f;
}

template<int COUT>
__global__ __launch_bounds__(256) void gather_max(
    const u16* __restrict__ UV, const int* __restrict__ idxb,
    u16* __restrict__ Xoutp) {
  constexpr int CG = COUT / 4;
  const int tid = blockIdx.x * 256 + threadIdx.x;
  const int cg = tid & (CG - 1);
  const int P = tid / CG;
  const int b = P >> 10;
  const int n = P & (NN - 1);

  const float4 vv = ubf4(*(const ushort4*)(UV + (size_t)P * (2 * COUT) + COUT + 4 * cg));
  const int4* ip = (const int4*)(idxb + (size_t)b * NKP + n * 16);
  float4 m = {-INFINITY, -INFINITY, -INFINITY, -INFINITY};
  #pragma unroll
  for (int kq = 0; kq < 4; ++kq) {
    const int4 iv = ip[kq];
    const int mr[4] = { iv.x & (NN - 1), iv.y & (NN - 1), iv.z & (NN - 1), iv.w & (NN - 1) };
    ushort4 uq[4];
    #pragma unroll
    for (int j = 0; j < 4; ++j)
      uq[j] = *(const ushort4*)(UV + (size_t)(b * NN + mr[j]) * (2 * COUT) + 4 * cg);
    #pragma unroll
    for (int j = 0; j < 4; ++j) {
      const float4 uu = ubf4(uq[j]);
      float4 s;
      s.x = uu.x + vv.x; s.y = uu.y + vv.y; s.z = uu.z + vv.z; s.w = uu.w + vv.w;
      m.x = fmaxf(m.x, fmaxf(s.x, 0.2f * s.x));
      m.y = fmaxf(m.y, fmaxf(s.y, 0.2f * s.y));
      m.z = fmaxf(m.z, fmaxf(s.z, 0.2f * s.z));
      m.w = fmaxf(m.w, fmaxf(s.w, 0.2f * s.w));
    }
  }
  union { ushort4 v; u16 s[4]; } pk;
  pk.s[0] = f2bf(m.x); pk.s[1] = f2bf(m.y); pk.s[2] = f2bf(m.z); pk.s[3] = f2bf(m.w);
  *(ushort4*)(Xoutp + (size_t)P * COUT + 4 * cg) = pk.v;
}

// ---------------- conv5 ----------------
__global__ __launch_bounds__(256) void conv5_mfma(
    const u16* __restrict__ X1P, const u16* __restrict__ X2P,
    const u16* __restrict__ X3P, const u16* __restrict__ X4P,
    const u16* __restrict__ w5b, const float* __restrict__ b5,
    float* __restrict__ PMAX, float* __restrict__ PSUM) {
  const int t = threadIdx.x;
  const int b = blockIdx.z;
  const int n0 = blockIdx.x * 64;
  const int w = t >> 6, l = t & 63;
  const int quad = l >> 4, l15 = l & 15;
  const int cq8 = quad * 8;
  const int ow0 = blockIdx.y * 256 + w * 64;

  f32x4 acc[4][4];
  #pragma unroll
  for (int i = 0; i < 4; ++i)
    #pragma unroll
    for (int j = 0; j < 4; ++j) acc[i][j] = (f32x4)0.f;

  #pragma unroll 4
  for (int k = 0; k < 16; ++k) {
    const int c = k * 32 + cq8;
    short8 bfr[4];
    #pragma unroll
    for (int pg = 0; pg < 4; ++pg) {
      const int n = n0 + pg * 16 + l15;
      const u16* src; int cc;
      if (c < 64)       { src = X1P + (size_t)(b * NN + n) * 64;  cc = c; }
      else if (c < 128) { src = X2P + (size_t)(b * NN + n) * 64;  cc = c - 64; }
      else if (c < 256) { src = X3P + (size_t)(b * NN + n) * 128; cc = c - 128; }
      else              { src = X4P + (size_t)(b * NN + n) * 256; cc = c - 256; }
      bfr[pg] = *(const short8*)(src + cc);
    }
    #pragma unroll
    for (int at = 0; at < 4; ++at) {
      const short8 af = *(const short8*)(w5b + ((size_t)(k * 1024 + ow0 + at * 16 + l15)) * 32 + cq8);
      #pragma unroll
      for (int pg = 0; pg < 4; ++pg) acc[at][pg] = MFMA16(af, bfr[pg], acc[at][pg]);
    }
  }

  #pragma unroll
  for (int at = 0; at < 4; ++at) {
    f32x4 pmx, psm;
    #pragma unroll
    for (int r = 0; r < 4; ++r) {
      const float bb = b5[ow0 + at * 16 + quad * 4 + r];
      float m = -INFINITY, s = 0.f;
      #pragma unroll
      for (int pg = 0; pg < 4; ++pg) {
        const float v = lrelu(acc[at][pg][r] + bb);
        m = fmaxf(m, v); s += v;
      }
      #pragma unroll
      for (int msk = 1; msk < 16; msk <<= 1) {
        m = fmaxf(m, __shfl_xor(m, msk));
        s += __shfl_xor(s, msk);
      }
      pmx[r] = m; psm[r] = s;
    }
    if (l15 == 0) {
      float* dm = PMAX + (size_t)(b * 16 + blockIdx.x) * 1024 + ow0 + at * 16 + quad * 4;
      float* ds = PSUM + (size_t)(b * 16 + blockIdx.x) * 1024 + ow0 + at * 16 + quad * 4;
      *(f32x4*)dm = pmx;
      *(f32x4*)ds = psm;
    }
  }
}

// ---------------- fc1 (inlined reduce) ----------------
__global__ __launch_bounds__(256) void fc1_kernel(
    const float* __restrict__ PMAX, const float* __restrict__ PSUM,
    const float* __restrict__ wl1t, const float* __restrict__ bn4_b,
    float* __restrict__ XF1) {
  __shared__ float xp[2048];
  __shared__ float red[64 * 5];
  const int t = threadIdx.x;
  const int b = blockIdx.y;
  for (int e = t; e < 1024; e += 256) {
    float m = -INFINITY, s = 0.f;
    #pragma unroll 4
    for (int pt = 0; pt < 16; ++pt) {
      m = fmaxf(m, PMAX[(size_t)(b * 16 + pt) * 1024 + e]);
      s += PSUM[(size_t)(b * 16 + pt) * 1024 + e];
    }
    xp[e] = m;
    xp[1024 + e] = s * (1.f / 1024.f);
  }
  __syncthreads();
  const int o = blockIdx.x * 64 + (t & 63);
  const int cq = t >> 6;
  float acc = 0.f;
  for (int c = cq * 512; c < cq * 512 + 512; ++c) acc = fmaf(wl1t[c * 512 + o], xp[c], acc);
  red[(t & 63) * 5 + cq] = acc;
  __syncthreads();
  if (t < 64) {
    const int oo = blockIdx.x * 64 + t;
    const float v = red[t * 5] + red[t * 5 + 1] + red[t * 5 + 2] + red[t * 5 + 3] + bn4_b[oo];
    XF1[b * 512 + oo] = lrelu(v);
  }
}

// ---------------- fc2 + fc3 merged ----------------
__global__ __launch_bounds__(256) void fc23_kernel(
    const float* __restrict__ XF1, const float* __restrict__ wl2t,
    const float* __restrict__ bl2, const float* __restrict__ bn5_g,
    const float* __restrict__ bn5_b, const float* __restrict__ wl3t,
    const float* __restrict__ bl3, float* __restrict__ out) {
  __shared__ float xf1s[512];
  __shared__ float xf2s[256];
  const int t = threadIdx.x;
  const int b = blockIdx.x;
  for (int e = t; e < 512; e += 256) xf1s[e] = XF1[b * 512 + e];
  __syncthreads();
  {
    float acc = 0.f;
    #pragma unroll 8
    for (int c = 0; c < 512; ++c) acc = fmaf(wl2t[c * 256 + t], xf1s[c], acc);
    const float bias = bl2[t] * (bn5_g[t] * BN_INV) + bn5_b[t];
    xf2s[t] = lrelu(acc + bias);
  }
  __syncthreads();
  if (t < 49) {
    float acc = 0.f;
    #pragma unroll 8
    for (int c = 0; c < 256; ++c) acc = fmaf(wl3t[c * 49 + t], xf2s[c], acc);
    out[b * 49 + t] = acc + bl3[t];
  }
}

// ---------------- host ----------------
extern "C" void kernel_launch(void* const* d_in, const int* in_sizes, int n_in,
                              void* d_out, int out_size, void* d_ws, size_t ws_size,
                              hipStream_t stream) {
  (void)in_sizes; (void)n_in; (void)out_size; (void)ws_size;
  const float* x     = (const float*)d_in[0];
  const float* m1_w0 = (const float*)d_in[1];
  const float* m1_g0 = (const float*)d_in[2];
  const float* m1_b0 = (const float*)d_in[3];
  const float* m1_wm = (const float*)d_in[4];
  const float* m1_gm = (const float*)d_in[5];
  const float* m1_bm = (const float*)d_in[6];
  const float* m1_w1 = (const float*)d_in[7];
  const float* m1_go = (const float*)d_in[8];
  const float* m1_bo = (const float*)d_in[9];
  const float* m1_ws = (const float*)d_in[10];
  const float* m1_gs = (const float*)d_in[11];
  const float* m1_bs = (const float*)d_in[12];
  const float* m2_w0 = (const float*)d_in[13];
  const float* m2_g0 = (const float*)d_in[14];
  const float* m2_b0 = (const float*)d_in[15];
  const float* m2_wm = (const float*)d_in[16];
  const float* m2_gm = (const float*)d_in[17];
  const float* m2_bm = (const float*)d_in[18];
  const float* m2_w1 = (const float*)d_in[19];
  const float* m2_go = (const float*)d_in[20];
  const float* m2_bo = (const float*)d_in[21];
  const float* m2_ws = (const float*)d_in[22];
  const float* m2_gs = (const float*)d_in[23];
  const float* m2_bs = (const float*)d_in[24];
  const float* w3    = (const float*)d_in[25];
  const float* g3    = (const float*)d_in[26];
  const float* b3    = (const float*)d_in[27];
  const float* w4    = (const float*)d_in[28];
  const float* g4    = (const float*)d_in[29];
  const float* b4    = (const float*)d_in[30];
  const float* w5    = (const float*)d_in[31];
  const float* g5    = (const float*)d_in[32];
  const float* b5    = (const float*)d_in[33];
  const float* wl1   = (const float*)d_in[34];
  const float* bn4_g = (const float*)d_in[35];
  const float* bn4_b = (const float*)d_in[36];
  const float* wl2   = (const float*)d_in[37];
  const float* bl2   = (const float*)d_in[38];
  const float* bn5_g = (const float*)d_in[39];
  const float* bn5_b = (const float*)d_in[40];
  const float* wl3   = (const float*)d_in[41];
  const float* bl3   = (const float*)d_in[42];

  char* wsb = (char*)d_ws;
  int*  IDX  = (int*)(wsb + OFF_IDX);
  u16*  X1P  = (u16*)(wsb + OFF_X1P);
  u16*  X2P  = (u16*)(wsb + OFF_X2P);
  u16*  X3P  = (u16*)(wsb + OFF_X3P);
  u16*  X4P  = (u16*)(wsb + OFF_X4P);
  u16*  MUV  = (u16*)(wsb + OFF_MUV);
  float* PMAX = (float*)(wsb + OFF_PMAX);
  float* PSUM = (float*)(wsb + OFF_PSUM);
  float* XF1  = (float*)(wsb + OFF_XF1);
  u16*  M1WM = (u16*)(wsb + OFF_M1WM);
  u16*  M1W1S = (u16*)(wsb + OFF_M1W1S);
  u16*  M2W0S = (u16*)(wsb + OFF_M2W0S);
  u16*  M2WM = (u16*)(wsb + OFF_M2WM);
  u16*  M2W1S = (u16*)(wsb + OFF_M2W1S);
  u16*  W3S  = (u16*)(wsb + OFF_W3S);
  u16*  W4S  = (u16*)(wsb + OFF_W4S);
  u16*  W5B  = (u16*)(wsb + OFF_W5);
  float* WL1T = (float*)(wsb + OFF_WL1T);
  float* WL2T = (float*)(wsb + OFF_WL2T);
  float* WL3T = (float*)(wsb + OFF_WL3T);
  u16*  UV3  = (u16*)(wsb + OFF_UV3);
  u16*  UV4  = (u16*)(wsb + OFF_UV4);

  PrepAll P;
  int st = 0;
  auto sset = [&](int i, const float* w, const float* g, u16* dst, int O, int C, int cpl2, int ch, int stk) {
    P.sa.seg[i].w = w; P.sa.seg[i].g = g; P.sa.seg[i].dst = dst; P.sa.seg[i].O = O; P.sa.seg[i].C = C;
    P.sa.seg[i].cpl2 = cpl2; P.sa.seg[i].ch = ch; P.sa.seg[i].stk = stk; P.sa.seg[i].start = st;
    st += O << cpl2;
  };
  sset(0, m1_wm, m1_gm, M1WM, 64, 64, 6, 0, 0);
  sset(1, m2_w0, m2_g0, M2W0S, 128, 64, 6, 0, 1);
  sset(2, m2_wm, m2_gm, M2WM, 64, 64, 6, 0, 0);
  sset(3, w3, g3, W3S, 256, 64, 6, 0, 1);
  sset(4, w4, g4, W4S, 512, 128, 7, 0, 1);
  sset(5, w5, g5, W5B, 1024, 512, 9, 0, 0);
  P.sa.total = st;

  P.w1a = m1_w1; P.wsa = m1_ws; P.goa = m1_go; P.gsa = m1_gs;
  P.w1b = m2_w1; P.wsb = m2_ws; P.gob = m2_go; P.gsb = m2_gs;
  P.dsta = M1W1S; P.dstb = M2W1S;

  int tt = 0;
  auto tset = [&](int i, const float* w, const float* g, float* dst, int O, int C) {
    P.ta.seg[i].w = w; P.ta.seg[i].g = g; P.ta.seg[i].dst = dst; P.ta.seg[i].O = O; P.ta.seg[i].C = C;
    P.ta.seg[i].start = tt; tt += O * C;
  };
  tset(0, wl1, bn4_g, WL1T, 512, 2048);
  tset(1, wl2, bn5_g, WL2T, 256, 512);
  tset(2, wl3, nullptr, WL3T, 49, 256);
  P.ta.total = tt;

  P.nA = (P.sa.total + 255) / 256;
  P.nB = (2 * 64 * 416 + 255) / 256;
  const int nC = (P.ta.total + 255) / 256;

  hipLaunchKernelGGL(prep_all, dim3(P.nA + P.nB + nC), dim3(256), 0, stream, P);

  hipLaunchKernelGGL(knn_mak1uv, dim3(4096), dim3(256), 0, stream,
                     x, IDX, m1_w0, m1_g0, m1_b0, MUV);

  hipLaunchKernelGGL(mak23_mfma, dim3(128, 1, BB), dim3(256), 0, stream,
                     x, IDX, MUV, M1WM, m1_bm, M1W1S, m1_bo, m1_bs, X1P);

  hipLaunchKernelGGL((dense_uv<64, 128>), dim3(8, 1, BB), dim3(256), 0, stream, X1P, M2W0S, m2_b0, MUV);
  hipLaunchKernelGGL(mak23_mfma, dim3(128, 1, BB), dim3(256), 0, stream,
                     x, IDX, MUV, M2WM, m2_bm, M2W1S, m2_bo, m2_bs, X2P);

  hipLaunchKernelGGL((dense_uv<64, 256>), dim3(16, 1, BB), dim3(256), 0, stream, X2P, W3S, b3, UV3);
  hipLaunchKernelGGL((gather_max<128>), dim3(1024), dim3(256), 0, stream, UV3, IDX, X3P);
  hipLaunchKernelGGL((dense_uv<128, 512>), dim3(16, 2, BB), dim3(256), 0, stream, X3P, W4S, b4, UV4);
  hipLaunchKernelGGL((gather_max<256>), dim3(2048), dim3(256), 0, stream, UV4, IDX, X4P);

  hipLaunchKernelGGL(conv5_mfma, dim3(16, 4, BB), dim3(256), 0, stream,
                     X1P, X2P, X3P, X4P, W5B, b5, PMAX, PSUM);

  hipLaunchKernelGGL(fc1_kernel, dim3(8, BB), dim3(256), 0, stream, PMAX, PSUM, WL1T, bn4_b, XF1);
  hipLaunchKernelGGL(fc23_kernel, dim3(BB), dim3(256), 0, stream,
                     XF1, WL2T, bl2, bn5_g, bn5_b, WL3T, bl3, (float*)d_out);
}

// Round 17
// 349.559 us; speedup vs baseline: 1.1124x; 1.0103x over previous
//
#include <hip/hip_runtime.h>
#include <math.h>

#define BB 8
#define NN 1024
#define KK 16
#define NKP (NN*KK)
#define BN_INV 0.99999500003749981f

typedef unsigned short u16;
typedef __attribute__((ext_vector_type(8))) short short8;
typedef __attribute__((ext_vector_type(4))) float f32x4;

#define MFMA16(a,b,c) __builtin_amdgcn_mfma_f32_16x16x32_bf16(a,b,c,0,0,0)

__device__ __forceinline__ float lrelu(float v) { return v >= 0.f ? v : 0.2f * v; }

__device__ __forceinline__ u16 f2bf(float f) {
  union { float f; unsigned u; } v; v.f = f;
  unsigned r = v.u + 0x7fff + ((v.u >> 16) & 1);
  return (u16)(r >> 16);
}
__device__ __forceinline__ float bf2f(u16 s) {
  union { unsigned u; float f; } v; v.u = ((unsigned)s) << 16;
  return v.f;
}

// ---------------- workspace byte offsets ----------------
constexpr size_t OFF_IDX   = 0;          // int[8*1024*16]
constexpr size_t OFF_X1P   = 524288;     // bf16 [8][1024][64]
constexpr size_t OFF_X2P   = 1572864;
constexpr size_t OFF_X3P   = 2621440;    // bf16 [8][1024][128]  (aliased as MUV during mak)
constexpr size_t OFF_MUV   = 2621440;    // bf16 [8][1024][128] u|v
constexpr size_t OFF_X4P   = 4718592;    // bf16 [8][1024][256]
constexpr size_t OFF_PMAX  = 8912896;    // f32 [8][16][1024]
constexpr size_t OFF_PSUM  = 9437184;
constexpr size_t OFF_XF1   = 10027008;   // f32 [8][512]
constexpr size_t OFF_M1WM  = 10055680;   // bf16 [2][64][32]
constexpr size_t OFF_M1W1S = 10063872;   // bf16 [13][64][32]
constexpr size_t OFF_M2W0S = 10117120;   // bf16 [2][128][32] stacked [Wd;Wc-Wd]
constexpr size_t OFF_M2WM  = 10133504;   // bf16 [2][64][32]
constexpr size_t OFF_M2W1S = 10141696;   // bf16 [13][64][32]
constexpr size_t OFF_W3S   = 10194944;   // bf16 [2][256][32] stacked
constexpr size_t OFF_W4S   = 10227712;   // bf16 [4][512][32] stacked
constexpr size_t OFF_W5    = 10358784;   // bf16 [16][1024][32]
constexpr size_t OFF_WL1T  = 11407360;   // f32 [2048][512]
constexpr size_t OFF_WL2T  = 15601664;   // f32 [512][256]
constexpr size_t OFF_WL3T  = 16125952;   // f32 [256][49]
constexpr size_t OFF_UV3   = 16177152;   // bf16 [8][1024][256] conv3 u|v
constexpr size_t OFF_UV4   = 20371456;   // bf16 [8][1024][512] conv4 u|v

// ---------------- merged weight prep (3-in-1) ----------------
struct SSeg { const float* w; const float* g; u16* dst; int O; int C; int cpl2; int ch; int stk; int start; };
struct SArgs { SSeg seg[6]; int total; };
struct TSeg { const float* w; const float* g; float* dst; int O; int C; int start; };
struct TArgs3 { TSeg seg[3]; int total; };
struct PrepAll {
  SArgs sa;
  const float *w1a, *wsa, *goa, *gsa, *w1b, *wsb, *gob, *gsb;
  u16 *dsta, *dstb;
  TArgs3 ta;
  int nA, nB;
};

__global__ __launch_bounds__(256) void prep_all(PrepAll P) {
  const int bx = blockIdx.x;
  const int t = threadIdx.x;
  if (bx < P.nA) {
    const int tid = bx * 256 + t;
    if (tid >= P.sa.total) return;
    int s = 0;
    #pragma unroll
    for (int i = 1; i < 6; ++i) if (tid >= P.sa.seg[i].start) s = i;
    const SSeg sg = P.sa.seg[s];
    const int e = tid - sg.start;
    const int o2 = e >> sg.cpl2;
    const int c = e & ((1 << sg.cpl2) - 1);
    float v = 0.f;
    if (sg.stk) {
      const int half = sg.O >> 1;
      const int o = o2 & (half - 1);
      const int CIN = 2 * sg.C;
      const float wd = sg.w[o * CIN + c];
      v = (o2 < half) ? wd : (sg.w[o * CIN + sg.C + c] - wd);
      v *= sg.g[o] * BN_INV;
    } else if (c < sg.C) {
      v = sg.w[o2 * sg.C + c];
      if (sg.ch && c >= sg.ch) v -= sg.w[o2 * sg.C + c - sg.ch];
      v *= sg.g[o2] * BN_INV;
    }
    sg.dst[(size_t)(c >> 5) * (sg.O * 32) + o2 * 32 + (c & 31)] = f2bf(v);
  } else if (bx < P.nA + P.nB) {
    const int tid = (bx - P.nA) * 256 + t;     // 2 sets of 64*416 = 26624
    const int set = (tid >= 26624) ? 1 : 0;
    const int id2 = tid - set * 26624;
    const float* w1 = set ? P.w1b : P.w1a;
    const float* wsm = set ? P.wsb : P.wsa;
    const float* go = set ? P.gob : P.goa;
    const float* gs = set ? P.gsb : P.gsa;
    u16* dst = set ? P.dstb : P.dsta;
    const int o = id2 / 416, ci = id2 - o * 416;
    float v = 0.f;
    if (ci < 384) {
      const int ii = ci >> 6, ch = ci & 63;
      const int base = (o * 24 + ii * 4) * 64 + ch;
      v = go[o] * BN_INV * (w1[base] + w1[base + 64] + w1[base + 128] + w1[base + 192]);
    } else if (ci < 390) {
      v = gs[o] * BN_INV * wsm[o * 6 + (ci - 384)];
    }
    dst[(size_t)(ci >> 5) * 2048 + o * 32 + (ci & 31)] = f2bf(v);
  } else {
    const int tid = (bx - P.nA - P.nB) * 256 + t;
    if (tid >= P.ta.total) return;
    int s = 0;
    #pragma unroll
    for (int i = 1; i < 3; ++i) if (tid >= P.ta.seg[i].start) s = i;
    const TSeg sg = P.ta.seg[s];
    const int e = tid - sg.start;
    const int c = e / sg.O;
    const int o = e - c * sg.O;
    float v = sg.w[o * sg.C + c];
    if (sg.g) v *= sg.g[o] * BN_INV;
    sg.dst[e] = v;
  }
}

// ---------------- KNN + mak1_uv merged ----------------
__global__ __launch_bounds__(256) void knn_mak1uv(
    const float* __restrict__ x, int* __restrict__ idxout,
    const float* __restrict__ w0, const float* __restrict__ g0,
    const float* __restrict__ b0, u16* __restrict__ MUV) {
  if (blockIdx.x < 2048) {
    const int wid  = (blockIdx.x * blockDim.x + threadIdx.x) >> 6;
    const int lane = threadIdx.x & 63;
    const int b = wid >> 10;
    const int n = wid & (NN - 1);
    const float* xb = x + b * 3 * NN;
    const float x0n = xb[n], x1n = xb[NN + n], x2n = xb[2 * NN + n];
    const float xxn = x0n * x0n + x1n * x1n + x2n * x2n;
    float pd[16];
    #pragma unroll
    for (int j = 0; j < 16; ++j) {
      const int m = j * 64 + lane;
      const float x0 = xb[m], x1 = xb[NN + m], x2 = xb[2 * NN + m];
      const float dot = x0n * x0 + x1n * x1 + x2n * x2;
      const float xxm = x0 * x0 + x1 * x1 + x2 * x2;
      pd[j] = 2.f * dot - xxn - xxm;
    }
    for (int r = 0; r < 16; ++r) {
      float bv = pd[0]; int bj = 0;
      #pragma unroll
      for (int j = 1; j < 16; ++j) if (pd[j] > bv) { bv = pd[j]; bj = j; }
      int bm = bj * 64 + lane;
      #pragma unroll
      for (int off = 32; off > 0; off >>= 1) {
        const float ov = __shfl_down(bv, off);
        const int   om = __shfl_down(bm, off);
        if (ov > bv || (ov == bv && om < bm)) { bv = ov; bm = om; }
      }
      bm = __shfl(bm, 0);
      if (lane == 0) idxout[wid * KK + r] = bm;
      const int  cj   = bm >> 6;
      const bool mine = (bm & 63) == lane;
      #pragma unroll
      for (int j = 0; j < 16; ++j) if (mine && j == cj) pd[j] = -INFINITY;
    }
  } else {
    const int tid = (blockIdx.x - 2048) * 256 + threadIdx.x;
    if (tid >= BB * NN * 64) return;
    const int o = tid & 63;
    const int p = tid >> 6;
    const int b = p >> 10, n = p & (NN - 1);
    const float* xb = x + b * 3 * NN;
    const float gg = g0[o] * BN_INV;
    float u = 0.f, v = 0.f;
    #pragma unroll
    for (int i = 0; i < 3; ++i) {
      const float wd = w0[o * 6 + i];
      const float wc = w0[o * 6 + 3 + i];
      const float c = xb[i * NN + n];
      u += wd * c;
      v += (wc - wd) * c;
    }
    MUV[(size_t)p * 128 + o]      = f2bf(gg * u);
    MUV[(size_t)p * 128 + 64 + o] = f2bf(gg * v + b0[o]);
  }
}

// ---------------- helpers ----------------
__device__ __forceinline__ short8 bfrag64(const u16* T, int pl, int quad, int c0) {
  const int pos = ((c0 >> 3) + quad) ^ (pl & 7);
  return *(const short8*)(T + pl * 64 + pos * 8);
}
__device__ __forceinline__ void writeD64(u16* T, int pl, int quad, const f32x4 a,
                                         const float* __restrict__ bias, int obase) {
  union { ushort4 v; u16 s[4]; } pk;
  #pragma unroll
  for (int r = 0; r < 4; ++r) pk.s[r] = f2bf(lrelu(a[r] + bias[obase + quad * 4 + r]));
  const int g = (obase + quad * 4) >> 3;
  const int pos = g ^ (pl & 7);
  *(ushort4*)(T + pl * 64 + pos * 8 + (quad & 1) * 4) = pk.v;
}

// ---------------- mak23 fused: 512 threads (8 waves share W1S), 2 points/wave ----------------
// LDS: W1S 12 chunks (49152 B) + 8 wave-private YM tiles (32768 B) = 81920 B -> 2 blocks/CU, 16 waves/CU.
// idt chunk (k=12) reads from global (4 KB, L1-hot).
__global__ __launch_bounds__(512) void mak23_mfma(
    const float* __restrict__ x, const int* __restrict__ idxb, const u16* __restrict__ MUV,
    const u16* __restrict__ wmb, const float* __restrict__ bmv,
    const u16* __restrict__ w1s, const float* __restrict__ bov, const float* __restrict__ bsv,
    u16* __restrict__ Xoutp) {
  __shared__ __align__(16) u16 W1S[12 * 2048];    // 49,152 B
  __shared__ __align__(16) u16 YMs[8][32 * 64];   // 32,768 B

  const int t = threadIdx.x;
  const int b = blockIdx.z;
  const int w = t >> 6, l = t & 63;
  const int quad = l >> 4, l15 = l & 15;
  const int cq8 = quad * 8;
  const int p0 = blockIdx.x * 16 + w * 2;   // 16 points per block, 2 per wave
  u16* myYM = YMs[w];
  const float* xb = x + b * 3 * NN;

  // cooperative W1S load -> LDS (swizzled): 3072 granules of 16 B, 6 per thread
  #pragma unroll
  for (int i = 0; i < 6; ++i) {
    const int g16 = i * 512 + t;                // 0..3071
    const int q = g16 & 3;
    const int row = (g16 >> 2) & 63;
    const int ch = g16 >> 8;                    // 0..11
    const uint4 val = *(const uint4*)(w1s + (size_t)g16 * 8);
    *(uint4*)(W1S + ch * 2048 + row * 32 + (q ^ (row & 3)) * 8) = val;
  }

  int nbr[2];
  #pragma unroll
  for (int pg = 0; pg < 2; ++pg)
    nbr[pg] = idxb[(size_t)(b * NN + p0 + pg) * 16 + l15] & (NN - 1);

  float ge[2][6];
  short8 bgv[2];
  #pragma unroll
  for (int pg = 0; pg < 2; ++pg) {
    const int ctr = p0 + pg;
    union { short8 v; u16 s[8]; } gq;
    gq.v = (short8)(short)0;
    #pragma unroll
    for (int i = 0; i < 3; ++i) {
      const float fc = xb[i * NN + ctr];
      ge[pg][i]     = xb[i * NN + nbr[pg]] - fc;
      ge[pg][3 + i] = fc;
      gq.s[i]     = f2bf(ge[pg][i]);
      gq.s[3 + i] = f2bf(ge[pg][3 + i]);
    }
    bgv[pg] = (quad == 0) ? gq.v : (short8)(short)0;
  }

  short8 bf[2][2];
  #pragma unroll
  for (int pg = 0; pg < 2; ++pg) {
    const u16* urow = MUV + (size_t)(b * NN + nbr[pg]) * 128;
    const u16* vrow = MUV + (size_t)(b * NN + p0 + pg) * 128 + 64;
    #pragma unroll
    for (int kc = 0; kc < 2; ++kc) {
      union { short8 v; u16 s[8]; } uu, vv, rr;
      uu.v = *(const short8*)(urow + kc * 32 + cq8);
      vv.v = *(const short8*)(vrow + kc * 32 + cq8);
      #pragma unroll
      for (int j = 0; j < 8; ++j) rr.s[j] = f2bf(lrelu(bf2f(uu.s[j]) + bf2f(vv.s[j])));
      bf[pg][kc] = rr.v;
    }
  }

  // ---- GEMM2 (wm from global; tiny, L1-hot) ----
  #pragma unroll
  for (int at = 0; at < 4; ++at) {
    f32x4 a2[2];
    #pragma unroll
    for (int pg = 0; pg < 2; ++pg) a2[pg] = (f32x4)0.f;
    #pragma unroll
    for (int kc = 0; kc < 2; ++kc) {
      const short8 af = *(const short8*)(wmb + (size_t)(kc * 64 + at * 16 + l15) * 32 + cq8);
      #pragma unroll
      for (int pg = 0; pg < 2; ++pg) a2[pg] = MFMA16(af, bf[pg][kc], a2[pg]);
    }
    #pragma unroll
    for (int pg = 0; pg < 2; ++pg) writeD64(myYM, pg * 16 + l15, quad, a2[pg], bmv, at * 16);
  }

  __syncthreads();   // W1S staging complete (staging overlapped prologue + GEMM2)

  // ---- GEMM3: ge-chunk A-frags from LDS; idt chunk from global ----
  short8 bf3[2][2];
  #pragma unroll
  for (int pg = 0; pg < 2; ++pg)
    #pragma unroll
    for (int kc = 0; kc < 2; ++kc)
      bf3[pg][kc] = bfrag64(myYM, pg * 16 + l15, quad, kc * 32);

  f32x4 acc[2][4];
  #pragma unroll
  for (int pg = 0; pg < 2; ++pg)
    #pragma unroll
    for (int at = 0; at < 4; ++at) acc[pg][at] = (f32x4)0.f;

  #pragma unroll
  for (int ii = 0; ii < 6; ++ii) {
    f32x4 tac[2][4];
    #pragma unroll
    for (int pg = 0; pg < 2; ++pg)
      #pragma unroll
      for (int at = 0; at < 4; ++at) tac[pg][at] = (f32x4)0.f;
    #pragma unroll
    for (int kc = 0; kc < 2; ++kc) {
      const int ch = ii * 2 + kc;
      #pragma unroll
      for (int at = 0; at < 4; ++at) {
        const int row = at * 16 + l15;
        const short8 af = *(const short8*)(W1S + ch * 2048 + row * 32 + (quad ^ (row & 3)) * 8);
        #pragma unroll
        for (int pg = 0; pg < 2; ++pg) tac[pg][at] = MFMA16(af, bf3[pg][kc], tac[pg][at]);
      }
    }
    #pragma unroll
    for (int pg = 0; pg < 2; ++pg) {
      const float g = ge[pg][ii];
      #pragma unroll
      for (int at = 0; at < 4; ++at) acc[pg][at] += g * tac[pg][at];
    }
  }
  #pragma unroll
  for (int at = 0; at < 4; ++at) {   // idt chunk from global
    const short8 af = *(const short8*)(w1s + (size_t)(12 * 64 + at * 16 + l15) * 32 + cq8);
    #pragma unroll
    for (int pg = 0; pg < 2; ++pg) acc[pg][at] = MFMA16(af, bgv[pg], acc[pg][at]);
  }

  #pragma unroll
  for (int pg = 0; pg < 2; ++pg) {
    u16* orow = Xoutp + (size_t)(b * NN + p0 + pg) * 64;
    #pragma unroll
    for (int at = 0; at < 4; ++at) {
      union { ushort4 v; u16 s[4]; } pk;
      #pragma unroll
      for (int r = 0; r < 4; ++r) {
        const int o = at * 16 + quad * 4 + r;
        float v = lrelu(acc[pg][at][r] + bov[o] + bsv[o]);
        v = fmaxf(v, __shfl_xor(v, 1));
        v = fmaxf(v, __shfl_xor(v, 2));
        v = fmaxf(v, __shfl_xor(v, 4));
        v = fmaxf(v, __shfl_xor(v, 8));
        pk.s[r] = f2bf(v);
      }
      if (l15 == 0) *(ushort4*)(orow + at * 16 + quad * 4) = pk.v;
    }
  }
}

// ---------------- dense UV GEMM ----------------
template<int CH, int COUT2>
__global__ __launch_bounds__(256) void dense_uv(
    const u16* __restrict__ srcp, const u16* __restrict__ w2,
    const float* __restrict__ bias, u16* __restrict__ UV) {
  constexpr int COUT = COUT2 / 2;
  constexpr int NCH = CH / 32;
  const int t = threadIdx.x;
  const int b = blockIdx.z;
  const int w = t >> 6, l = t & 63;
  const int quad = l >> 4, l15 = l & 15;
  const int cq8 = quad * 8;
  int n0, ow0;
  if constexpr (COUT2 >= 256) { n0 = blockIdx.x * 64; ow0 = blockIdx.y * 256 + w * 64; }
  else { n0 = blockIdx.x * 128 + (w >> 1) * 64; ow0 = (w & 1) * 64; }

  f32x4 acc[4][4];
  #pragma unroll
  for (int i = 0; i < 4; ++i)
    #pragma unroll
    for (int j = 0; j < 4; ++j) acc[i][j] = (f32x4)0.f;

  #pragma unroll
  for (int k = 0; k < NCH; ++k) {
    short8 bfr[4];
    #pragma unroll
    for (int pg = 0; pg < 4; ++pg) {
      const int n = n0 + pg * 16 + l15;
      bfr[pg] = *(const short8*)(srcp + (size_t)(b * NN + n) * CH + k * 32 + cq8);
    }
    #pragma unroll
    for (int at = 0; at < 4; ++at) {
      const short8 af = *(const short8*)(w2 + ((size_t)(k * COUT2 + ow0 + at * 16 + l15)) * 32 + cq8);
      #pragma unroll
      for (int pg = 0; pg < 4; ++pg) acc[at][pg] = MFMA16(af, bfr[pg], acc[at][pg]);
    }
  }

  #pragma unroll
  for (int at = 0; at < 4; ++at) {
    const int o0 = ow0 + at * 16 + quad * 4;
    const bool isv = (o0 >= COUT);
    float bb[4];
    #pragma unroll
    for (int r = 0; r < 4; ++r) bb[r] = isv ? bias[o0 + r - COUT] : 0.f;
    #pragma unroll
    for (int pg = 0; pg < 4; ++pg) {
      const int n = n0 + pg * 16 + l15;
      union { ushort4 v; u16 s[4]; } pk;
      #pragma unroll
      for (int r = 0; r < 4; ++r) pk.s[r] = f2bf(acc[at][pg][r] + bb[r]);
      *(ushort4*)(UV + (size_t)(b * NN + n) * COUT2 + o0) = pk.v;
    }
  }
}

// ---------------- gather-max ----------------
__device__ __forceinline__ float4 ubf4(ushort4 q) {
  float4 f;
  f.x = bf2f(q.x); f.y = bf2f(q.y); f.z = bf2f(q.z); f.w = bf2f(q.w);
  return f;
}

template<int COUT>
__global__ __launch_bounds__(256) void gather_max(
    const u16* __restrict__ UV, const int* __restrict__ idxb,
    u16* __restrict__ Xoutp) {
  constexpr int CG = COUT / 4;
  const int tid = blockIdx.x * 256 + threadIdx.x;
  const int cg = tid & (CG - 1);
  const int P = tid / CG;
  const int b = P >> 10;
  const int n = P & (NN - 1);

  const float4 vv = ubf4(*(const ushort4*)(UV + (size_t)P * (2 * COUT) + COUT + 4 * cg));
  const int4* ip = (const int4*)(idxb + (size_t)b * NKP + n * 16);
  float4 m = {-INFINITY, -INFINITY, -INFINITY, -INFINITY};
  #pragma unroll
  for (int kq = 0; kq < 4; ++kq) {
    const int4 iv = ip[kq];
    const int mr[4] = { iv.x & (NN - 1), iv.y & (NN - 1), iv.z & (NN - 1), iv.w & (NN - 1) };
    ushort4 uq[4];
    #pragma unroll
    for (int j = 0; j < 4; ++j)
      uq[j] = *(const ushort4*)(UV + (size_t)(b * NN + mr[j]) * (2 * COUT) + 4 * cg);
    #pragma unroll
    for (int j = 0; j < 4; ++j) {
      const float4 uu = ubf4(uq[j]);
      float4 s;
      s.x = uu.x + vv.x; s.y = uu.y + vv.y; s.z = uu.z + vv.z; s.w = uu.w + vv.w;
      m.x = fmaxf(m.x, fmaxf(s.x, 0.2f * s.x));
      m.y = fmaxf(m.y, fmaxf(s.y, 0.2f * s.y));
      m.z = fmaxf(m.z, fmaxf(s.z, 0.2f * s.z));
      m.w = fmaxf(m.w, fmaxf(s.w, 0.2f * s.w));
    }
  }
  union { ushort4 v; u16 s[4]; } pk;
  pk.s[0] = f2bf(m.x); pk.s[1] = f2bf(m.y); pk.s[2] = f2bf(m.z); pk.s[3] = f2bf(m.w);
  *(ushort4*)(Xoutp + (size_t)P * COUT + 4 * cg) = pk.v;
}

// ---------------- conv5 ----------------
__global__ __launch_bounds__(256) void conv5_mfma(
    const u16* __restrict__ X1P, const u16* __restrict__ X2P,
    const u16* __restrict__ X3P, const u16* __restrict__ X4P,
    const u16* __restrict__ w5b, const float* __restrict__ b5,
    float* __restrict__ PMAX, float* __restrict__ PSUM) {
  const int t = threadIdx.x;
  const int b = blockIdx.z;
  const int n0 = blockIdx.x * 64;
  const int w = t >> 6, l = t & 63;
  const int quad = l >> 4, l15 = l & 15;
  const int cq8 = quad * 8;
  const int ow0 = blockIdx.y * 256 + w * 64;

  f32x4 acc[4][4];
  #pragma unroll
  for (int i = 0; i < 4; ++i)
    #pragma unroll
    for (int j = 0; j < 4; ++j) acc[i][j] = (f32x4)0.f;

  #pragma unroll 4
  for (int k = 0; k < 16; ++k) {
    const int c = k * 32 + cq8;
    short8 bfr[4];
    #pragma unroll
    for (int pg = 0; pg < 4; ++pg) {
      const int n = n0 + pg * 16 + l15;
      const u16* src; int cc;
      if (c < 64)       { src = X1P + (size_t)(b * NN + n) * 64;  cc = c; }
      else if (c < 128) { src = X2P + (size_t)(b * NN + n) * 64;  cc = c - 64; }
      else if (c < 256) { src = X3P + (size_t)(b * NN + n) * 128; cc = c - 128; }
      else              { src = X4P + (size_t)(b * NN + n) * 256; cc = c - 256; }
      bfr[pg] = *(const short8*)(src + cc);
    }
    #pragma unroll
    for (int at = 0; at < 4; ++at) {
      const short8 af = *(const short8*)(w5b + ((size_t)(k * 1024 + ow0 + at * 16 + l15)) * 32 + cq8);
      #pragma unroll
      for (int pg = 0; pg < 4; ++pg) acc[at][pg] = MFMA16(af, bfr[pg], acc[at][pg]);
    }
  }

  #pragma unroll
  for (int at = 0; at < 4; ++at) {
    f32x4 pmx, psm;
    #pragma unroll
    for (int r = 0; r < 4; ++r) {
      const float bb = b5[ow0 + at * 16 + quad * 4 + r];
      float m = -INFINITY, s = 0.f;
      #pragma unroll
      for (int pg = 0; pg < 4; ++pg) {
        const float v = lrelu(acc[at][pg][r] + bb);
        m = fmaxf(m, v); s += v;
      }
      #pragma unroll
      for (int msk = 1; msk < 16; msk <<= 1) {
        m = fmaxf(m, __shfl_xor(m, msk));
        s += __shfl_xor(s, msk);
      }
      pmx[r] = m; psm[r] = s;
    }
    if (l15 == 0) {
      float* dm = PMAX + (size_t)(b * 16 + blockIdx.x) * 1024 + ow0 + at * 16 + quad * 4;
      float* ds = PSUM + (size_t)(b * 16 + blockIdx.x) * 1024 + ow0 + at * 16 + quad * 4;
      *(f32x4*)dm = pmx;
      *(f32x4*)ds = psm;
    }
  }
}

// ---------------- fc1 (inlined reduce) ----------------
__global__ __launch_bounds__(256) void fc1_kernel(
    const float* __restrict__ PMAX, const float* __restrict__ PSUM,
    const float* __restrict__ wl1t, const float* __restrict__ bn4_b,
    float* __restrict__ XF1) {
  __shared__ float xp[2048];
  __shared__ float red[64 * 5];
  const int t = threadIdx.x;
  const int b = blockIdx.y;
  for (int e = t; e < 1024; e += 256) {
    float m = -INFINITY, s = 0.f;
    #pragma unroll 4
    for (int pt = 0; pt < 16; ++pt) {
      m = fmaxf(m, PMAX[(size_t)(b * 16 + pt) * 1024 + e]);
      s += PSUM[(size_t)(b * 16 + pt) * 1024 + e];
    }
    xp[e] = m;
    xp[1024 + e] = s * (1.f / 1024.f);
  }
  __syncthreads();
  const int o = blockIdx.x * 64 + (t & 63);
  const int cq = t >> 6;
  float acc = 0.f;
  for (int c = cq * 512; c < cq * 512 + 512; ++c) acc = fmaf(wl1t[c * 512 + o], xp[c], acc);
  red[(t & 63) * 5 + cq] = acc;
  __syncthreads();
  if (t < 64) {
    const int oo = blockIdx.x * 64 + t;
    const float v = red[t * 5] + red[t * 5 + 1] + red[t * 5 + 2] + red[t * 5 + 3] + bn4_b[oo];
    XF1[b * 512 + oo] = lrelu(v);
  }
}

// ---------------- fc2 + fc3 merged ----------------
__global__ __launch_bounds__(256) void fc23_kernel(
    const float* __restrict__ XF1, const float* __restrict__ wl2t,
    const float* __restrict__ bl2, const float* __restrict__ bn5_g,
    const float* __restrict__ bn5_b, const float* __restrict__ wl3t,
    const float* __restrict__ bl3, float* __restrict__ out) {
  __shared__ float xf1s[512];
  __shared__ float xf2s[256];
  const int t = threadIdx.x;
  const int b = blockIdx.x;
  for (int e = t; e < 512; e += 256) xf1s[e] = XF1[b * 512 + e];
  __syncthreads();
  {
    float acc = 0.f;
    #pragma unroll 8
    for (int c = 0; c < 512; ++c) acc = fmaf(wl2t[c * 256 + t], xf1s[c], acc);
    const float bias = bl2[t] * (bn5_g[t] * BN_INV) + bn5_b[t];
    xf2s[t] = lrelu(acc + bias);
  }
  __syncthreads();
  if (t < 49) {
    float acc = 0.f;
    #pragma unroll 8
    for (int c = 0; c < 256; ++c) acc = fmaf(wl3t[c * 49 + t], xf2s[c], acc);
    out[b * 49 + t] = acc + bl3[t];
  }
}

// ---------------- host ----------------
extern "C" void kernel_launch(void* const* d_in, const int* in_sizes, int n_in,
                              void* d_out, int out_size, void* d_ws, size_t ws_size,
                              hipStream_t stream) {
  (void)in_sizes; (void)n_in; (void)out_size; (void)ws_size;
  const float* x     = (const float*)d_in[0];
  const float* m1_w0 = (const float*)d_in[1];
  const float* m1_g0 = (const float*)d_in[2];
  const float* m1_b0 = (const float*)d_in[3];
  const float* m1_wm = (const float*)d_in[4];
  const float* m1_gm = (const float*)d_in[5];
  const float* m1_bm = (const float*)d_in[6];
  const float* m1_w1 = (const float*)d_in[7];
  const float* m1_go = (const float*)d_in[8];
  const float* m1_bo = (const float*)d_in[9];
  const float* m1_ws = (const float*)d_in[10];
  const float* m1_gs = (const float*)d_in[11];
  const float* m1_bs = (const float*)d_in[12];
  const float* m2_w0 = (const float*)d_in[13];
  const float* m2_g0 = (const float*)d_in[14];
  const float* m2_b0 = (const float*)d_in[15];
  const float* m2_wm = (const float*)d_in[16];
  const float* m2_gm = (const float*)d_in[17];
  const float* m2_bm = (const float*)d_in[18];
  const float* m2_w1 = (const float*)d_in[19];
  const float* m2_go = (const float*)d_in[20];
  const float* m2_bo = (const float*)d_in[21];
  const float* m2_ws = (const float*)d_in[22];
  const float* m2_gs = (const float*)d_in[23];
  const float* m2_bs = (const float*)d_in[24];
  const float* w3    = (const float*)d_in[25];
  const float* g3    = (const float*)d_in[26];
  const float* b3    = (const float*)d_in[27];
  const float* w4    = (const float*)d_in[28];
  const float* g4    = (const float*)d_in[29];
  const float* b4    = (const float*)d_in[30];
  const float* w5    = (const float*)d_in[31];
  const float* g5    = (const float*)d_in[32];
  const float* b5    = (const float*)d_in[33];
  const float* wl1   = (const float*)d_in[34];
  const float* bn4_g = (const float*)d_in[35];
  const float* bn4_b = (const float*)d_in[36];
  const float* wl2   = (const float*)d_in[37];
  const float* bl2   = (const float*)d_in[38];
  const float* bn5_g = (const float*)d_in[39];
  const float* bn5_b = (const float*)d_in[40];
  const float* wl3   = (const float*)d_in[41];
  const float* bl3   = (const float*)d_in[42];

  char* wsb = (char*)d_ws;
  int*  IDX  = (int*)(wsb + OFF_IDX);
  u16*  X1P  = (u16*)(wsb + OFF_X1P);
  u16*  X2P  = (u16*)(wsb + OFF_X2P);
  u16*  X3P  = (u16*)(wsb + OFF_X3P);
  u16*  X4P  = (u16*)(wsb + OFF_X4P);
  u16*  MUV  = (u16*)(wsb + OFF_MUV);
  float* PMAX = (float*)(wsb + OFF_PMAX);
  float* PSUM = (float*)(wsb + OFF_PSUM);
  float* XF1  = (float*)(wsb + OFF_XF1);
  u16*  M1WM = (u16*)(wsb + OFF_M1WM);
  u16*  M1W1S = (u16*)(wsb + OFF_M1W1S);
  u16*  M2W0S = (u16*)(wsb + OFF_M2W0S);
  u16*  M2WM = (u16*)(wsb + OFF_M2WM);
  u16*  M2W1S = (u16*)(wsb + OFF_M2W1S);
  u16*  W3S  = (u16*)(wsb + OFF_W3S);
  u16*  W4S  = (u16*)(wsb + OFF_W4S);
  u16*  W5B  = (u16*)(wsb + OFF_W5);
  float* WL1T = (float*)(wsb + OFF_WL1T);
  float* WL2T = (float*)(wsb + OFF_WL2T);
  float* WL3T = (float*)(wsb + OFF_WL3T);
  u16*  UV3  = (u16*)(wsb + OFF_UV3);
  u16*  UV4  = (u16*)(wsb + OFF_UV4);

  PrepAll P;
  int st = 0;
  auto sset = [&](int i, const float* w, const float* g, u16* dst, int O, int C, int cpl2, int ch, int stk) {
    P.sa.seg[i].w = w; P.sa.seg[i].g = g; P.sa.seg[i].dst = dst; P.sa.seg[i].O = O; P.sa.seg[i].C = C;
    P.sa.seg[i].cpl2 = cpl2; P.sa.seg[i].ch = ch; P.sa.seg[i].stk = stk; P.sa.seg[i].start = st;
    st += O << cpl2;
  };
  sset(0, m1_wm, m1_gm, M1WM, 64, 64, 6, 0, 0);
  sset(1, m2_w0, m2_g0, M2W0S, 128, 64, 6, 0, 1);
  sset(2, m2_wm, m2_gm, M2WM, 64, 64, 6, 0, 0);
  sset(3, w3, g3, W3S, 256, 64, 6, 0, 1);
  sset(4, w4, g4, W4S, 512, 128, 7, 0, 1);
  sset(5, w5, g5, W5B, 1024, 512, 9, 0, 0);
  P.sa.total = st;

  P.w1a = m1_w1; P.wsa = m1_ws; P.goa = m1_go; P.gsa = m1_gs;
  P.w1b = m2_w1; P.wsb = m2_ws; P.gob = m2_go; P.gsb = m2_gs;
  P.dsta = M1W1S; P.dstb = M2W1S;

  int tt = 0;
  auto tset = [&](int i, const float* w, const float* g, float* dst, int O, int C) {
    P.ta.seg[i].w = w; P.ta.seg[i].g = g; P.ta.seg[i].dst = dst; P.ta.seg[i].O = O; P.ta.seg[i].C = C;
    P.ta.seg[i].start = tt; tt += O * C;
  };
  tset(0, wl1, bn4_g, WL1T, 512, 2048);
  tset(1, wl2, bn5_g, WL2T, 256, 512);
  tset(2, wl3, nullptr, WL3T, 49, 256);
  P.ta.total = tt;

  P.nA = (P.sa.total + 255) / 256;
  P.nB = (2 * 64 * 416 + 255) / 256;
  const int nC = (P.ta.total + 255) / 256;

  hipLaunchKernelGGL(prep_all, dim3(P.nA + P.nB + nC), dim3(256), 0, stream, P);

  hipLaunchKernelGGL(knn_mak1uv, dim3(4096), dim3(256), 0, stream,
                     x, IDX, m1_w0, m1_g0, m1_b0, MUV);

  hipLaunchKernelGGL(mak23_mfma, dim3(64, 1, BB), dim3(512), 0, stream,
                     x, IDX, MUV, M1WM, m1_bm, M1W1S, m1_bo, m1_bs, X1P);

  hipLaunchKernelGGL((dense_uv<64, 128>), dim3(8, 1, BB), dim3(256), 0, stream, X1P, M2W0S, m2_b0, MUV);
  hipLaunchKernelGGL(mak23_mfma, dim3(64, 1, BB), dim3(512), 0, stream,
                     x, IDX, MUV, M2WM, m2_bm, M2W1S, m2_bo, m2_bs, X2P);

  hipLaunchKernelGGL((dense_uv<64, 256>), dim3(16, 1, BB), dim3(256), 0, stream, X2P, W3S, b3, UV3);
  hipLaunchKernelGGL((gather_max<128>), dim3(1024), dim3(256), 0, stream, UV3, IDX, X3P);
  hipLaunchKernelGGL((dense_uv<128, 512>), dim3(16, 2, BB), dim3(256), 0, stream, X3P, W4S, b4, UV4);
  hipLaunchKernelGGL((gather_max<256>), dim3(2048), dim3(256), 0, stream, UV4, IDX, X4P);

  hipLaunchKernelGGL(conv5_mfma, dim3(16, 4, BB), dim3(256), 0, stream,
                     X1P, X2P, X3P, X4P, W5B, b5, PMAX, PSUM);

  hipLaunchKernelGGL(fc1_kernel, dim3(8, BB), dim3(256), 0, stream, PMAX, PSUM, WL1T, bn4_b, XF1);
  hipLaunchKernelGGL(fc23_kernel, dim3(BB), dim3(256), 0, stream,
                     XF1, WL2T, bl2, bn5_g, bn5_b, WL3T, bl3, (float*)d_out);
}